// Round 5
// baseline (958.153 us; speedup 1.0000x reference)
//
#include <hip/hip_runtime.h>
#include <math.h>

#define BB 32
#define NN 8400
#define MM 32
#define NC 80
#define PD 85
#define TOPK 10
#define NCHUNK 56
#define CHSZ 150             // NN / NCHUNK
#define FLT_BIG 3.4e38f

__device__ __forceinline__ float sigmoidf_(float x) { return 1.0f / (1.0f + expf(-x)); }
__device__ __forceinline__ float bcef_(float x, float t) {
    return fmaxf(x, 0.0f) - x * t + log1pf(expf(-fabsf(x)));
}

// ---- Kernel AB: wave-per-2-rows, zero LDS, fully coalesced ----------------
__global__ void __launch_bounds__(256) kAB(const float* __restrict__ pred,
                                           const float* __restrict__ tgt,
                                           float* __restrict__ objlogit,
                                           float2* __restrict__ cv2) {
    const int lane = threadIdx.x & 63;
    const int gw = blockIdx.x * (blockDim.x >> 6) + (threadIdx.x >> 6);
    const int nw = gridDim.x * (blockDim.x >> 6);
    const int rs = lane >> 5, g = lane & 31;
    const int NPAIR = BB * (NN / 2);

    for (int pair = gw; pair < NPAIR; pair += nw) {
        const int b = pair / (NN / 2);
        const int r0 = (pair - b * (NN / 2)) * 2;
        const size_t off = ((size_t)b * NN + r0) * PD;
        float x0 = pred[off + lane];                       // pos 0..63
        float x1 = pred[off + 64 + lane];                  // pos 64..127
        float x2 = (lane < 42) ? pred[off + 128 + lane] : 0.0f; // pos 128..169

        // row headers: row0 pos 0..4, row1 pos 85..89
        float cx0 = __shfl(x0, 0), cy0 = __shfl(x0, 1), w0 = __shfl(x0, 2), h0 = __shfl(x0, 3), ol0 = __shfl(x0, 4);
        float cx1 = __shfl(x1, 21), cy1 = __shfl(x1, 22), w1 = __shfl(x1, 23), h1 = __shfl(x1, 24), ol1 = __shfl(x1, 25);
        float so0 = sigmoidf_(ol0), so1 = sigmoidf_(ol1);
        if (lane == 0) objlogit[(size_t)b * NN + r0] = ol0;
        else if (lane == 1) objlogit[(size_t)b * NN + r0 + 1] = ol1;

        // class lq terms distributed one-per-lane
        float a0 = 0.0f, a1 = 0.0f;
        if (lane >= 5)  a0 += logf(1.0f - sqrtf(sigmoidf_(x0) * so0) + 1e-7f);
        if (lane < 21)  a0 += logf(1.0f - sqrtf(sigmoidf_(x1) * so0) + 1e-7f);
        if (lane >= 26) a1 += logf(1.0f - sqrtf(sigmoidf_(x1) * so1) + 1e-7f);
        if (lane < 42)  a1 += logf(1.0f - sqrtf(sigmoidf_(x2) * so1) + 1e-7f);
        #pragma unroll
        for (int o = 32; o; o >>= 1) { a0 += __shfl_xor(a0, o); a1 += __shfl_xor(a1, o); }
        float base0 = -a0, base1 = -a1;

        float cxs = rs ? cx1 : cx0, cys = rs ? cy1 : cy0;
        float ws_ = rs ? w1 : w0, hs_ = rs ? h1 : h0;
        float sos = rs ? so1 : so0, bases = rs ? base1 : base0;
        float px1 = cxs - ws_ * 0.5f, py1 = cys - hs_ * 0.5f;
        float px2 = cxs + ws_ * 0.5f, py2 = cys + hs_ * 0.5f;
        float pa = fmaxf(px2 - px1, 0.0f) * fmaxf(py2 - py1, 0.0f);

        const float* t = tgt + ((size_t)b * MM + g) * 5;
        int gcls = (int)t[0];
        float gx1 = t[1] - t[3] * 0.5f, gy1 = t[2] - t[4] * 0.5f;
        float gx2 = t[1] + t[3] * 0.5f, gy2 = t[2] + t[4] * 0.5f;
        float ga = fmaxf(gx2 - gx1, 0.0f) * fmaxf(gy2 - gy1, 0.0f);

        int posn = rs * 85 + 5 + gcls;
        int k = posn >> 6, ls = posn & 63;
        float g0 = __shfl(x0, ls), g1 = __shfl(x1, ls), g2 = __shfl(x2, ls);
        float cl = (k == 0) ? g0 : ((k == 1) ? g1 : g2);

        float ix1 = fmaxf(gx1, px1), iy1 = fmaxf(gy1, py1);
        float ix2 = fminf(gx2, px2), iy2 = fminf(gy2, py2);
        float inter = fmaxf(ix2 - ix1, 0.0f) * fmaxf(iy2 - iy1, 0.0f);
        float uni = ga + pa - inter + 1e-7f;
        float iou = inter / uni;
        bool inb = (cxs > gx1) && (cxs < gx2) && (cys > gy1) && (cys < gy2);
        float s = sqrtf(sigmoidf_(cl) * sos);
        float lp = logf(s + 1e-7f);
        float lq = logf(1.0f - s + 1e-7f);
        float cc = bases - lp + lq;
        float co = cc + 3.0f * (-logf(iou + 1e-8f)) + (inb ? 0.0f : 100000.0f);

        cv2[((size_t)b * NN + r0) * MM + lane] = make_float2(co, inb ? iou : 0.0f);
    }
}

// ---- Kernel C1: per-(image, n-chunk) exact partial top-10 lists -----------
__global__ void __launch_bounds__(256) kC1(const float2* __restrict__ cv2,
                                           float* __restrict__ piou,
                                           float2* __restrict__ pcvn) {
    const int chunk = blockIdx.x, b = blockIdx.y;
    const int t = threadIdx.x;
    const int g = t & 31, sub = t >> 5;      // 8 n-lanes per g
    const int c0 = chunk * CHSZ;

    float ti[TOPK], cv[TOPK]; int ci[TOPK];
    #pragma unroll
    for (int j = 0; j < TOPK; ++j) { ti[j] = -1.0f; cv[j] = FLT_BIG; ci[j] = 0x7fffffff; }

    const float2* basep = cv2 + ((size_t)b * NN + c0) * MM + g;
    for (int n = sub; n < CHSZ; n += 8) {     // per-thread n strictly increasing
        float2 e = basep[(size_t)n * MM];
        float c = e.x, v = e.y;
        if (v > ti[TOPK - 1]) {
            ti[TOPK - 1] = v;
            #pragma unroll
            for (int j = TOPK - 1; j > 0; --j)
                if (ti[j] > ti[j - 1]) { float tmp = ti[j - 1]; ti[j - 1] = ti[j]; ti[j] = tmp; }
        }
        if (c < cv[TOPK - 1]) {               // strict <: equal cost keeps smaller n
            cv[TOPK - 1] = c; ci[TOPK - 1] = c0 + n;
            #pragma unroll
            for (int j = TOPK - 1; j > 0; --j)
                if (cv[j] < cv[j - 1]) {
                    float tv = cv[j - 1]; cv[j - 1] = cv[j]; cv[j] = tv;
                    int tn = ci[j - 1]; ci[j - 1] = ci[j]; ci[j] = tn;
                }
        }
    }

    __shared__ float siou[256 * TOPK];
    __shared__ float scv[256 * TOPK];
    __shared__ int   scn[256 * TOPK];
    #pragma unroll
    for (int j = 0; j < TOPK; ++j) {
        siou[t * TOPK + j] = ti[j];
        scv[t * TOPK + j] = cv[j];
        scn[t * TOPK + j] = ci[j];
    }
    __syncthreads();

    if (t < 32) {   // merge the 8 sub-lists for g = t (exact: disjoint n sets)
        float mi[TOPK], mc[TOPK]; int mn[TOPK];
        #pragma unroll
        for (int j = 0; j < TOPK; ++j) { mi[j] = -1.0f; mc[j] = FLT_BIG; mn[j] = 0x7fffffff; }
        for (int sidx = 0; sidx < 8; ++sidx) {
            int src = (t + sidx * 32) * TOPK;
            #pragma unroll
            for (int j = 0; j < TOPK; ++j) {
                float v = siou[src + j];
                if (v > mi[TOPK - 1]) {
                    mi[TOPK - 1] = v;
                    #pragma unroll
                    for (int q = TOPK - 1; q > 0; --q)
                        if (mi[q] > mi[q - 1]) { float tm = mi[q - 1]; mi[q - 1] = mi[q]; mi[q] = tm; }
                }
                float c = scv[src + j]; int n2 = scn[src + j];
                if (c < mc[TOPK - 1] || (c == mc[TOPK - 1] && n2 < mn[TOPK - 1])) {
                    mc[TOPK - 1] = c; mn[TOPK - 1] = n2;
                    #pragma unroll
                    for (int q = TOPK - 1; q > 0; --q)
                        if (mc[q] < mc[q - 1] || (mc[q] == mc[q - 1] && mn[q] < mn[q - 1])) {
                            float tv = mc[q - 1]; mc[q - 1] = mc[q]; mc[q] = tv;
                            int tn = mn[q - 1]; mn[q - 1] = mn[q]; mn[q] = tn;
                        }
                }
            }
        }
        size_t po = (((size_t)b * NCHUNK + chunk) * MM + t) * TOPK;
        #pragma unroll
        for (int j = 0; j < TOPK; ++j) {
            piou[po + j] = mi[j];
            pcvn[po + j] = make_float2(mc[j], __int_as_float(mn[j]));
        }
    }
}

// ---- Kernel C2: per-(b,g) final merge -> dyn_k + assignment ---------------
__global__ void __launch_bounds__(64) kC2(const float* __restrict__ piou,
                                          const float2* __restrict__ pcvn,
                                          unsigned int* __restrict__ mask) {
    const int g = blockIdx.x, b = blockIdx.y, lane = threadIdx.x;
    const int NCAND = NCHUNK * TOPK;   // 560
    __shared__ float civ[NCAND];
    __shared__ float ccv[NCAND];
    __shared__ int   ccn[NCAND];
    for (int i = lane; i < NCAND; i += 64) {
        int ch = i / TOPK, j = i - ch * TOPK;
        size_t po = (((size_t)b * NCHUNK + ch) * MM + g) * TOPK + j;
        civ[i] = piou[po];
        float2 e = pcvn[po];
        ccv[i] = e.x; ccn[i] = __float_as_int(e.y);
    }
    __syncthreads();

    // sum of top-10 ious, accumulated in descending order (matches ref)
    float ssum = 0.0f;
    for (int p = 0; p < TOPK; ++p) {
        float bv = -2.0f; int bp = 0x7fffffff;
        for (int i = lane; i < NCAND; i += 64) {
            float v = civ[i];
            if (v > bv) { bv = v; bp = i; }
        }
        #pragma unroll
        for (int o = 32; o; o >>= 1) {
            float ov = __shfl_xor(bv, o); int op = __shfl_xor(bp, o);
            if (ov > bv || (ov == bv && op < bp)) { bv = ov; bp = op; }
        }
        ssum += bv;
        if (lane == 0) civ[bp] = -2.0f;
        __syncthreads();
    }
    int dynk = (int)ssum;              // trunc toward zero; sum in [0,10)
    if (dynk < 1) dynk = 1;
    if (dynk > TOPK) dynk = TOPK;

    // dyn_k lexicographically-smallest (cost, n)
    for (int p = 0; p < dynk; ++p) {
        float bv = FLT_BIG; int bn = 0x7fffffff, bp = -1;
        for (int i = lane; i < NCAND; i += 64) {
            float v = ccv[i]; int n2 = ccn[i];
            if (v < bv || (v == bv && n2 < bn)) { bv = v; bn = n2; bp = i; }
        }
        #pragma unroll
        for (int o = 32; o; o >>= 1) {
            float ov = __shfl_xor(bv, o); int on = __shfl_xor(bn, o); int op = __shfl_xor(bp, o);
            if (ov < bv || (ov == bv && on < bn)) { bv = ov; bn = on; bp = op; }
        }
        if (lane == 0) {
            ccv[bp] = FLT_BIG; ccn[bp] = 0x7fffffff;
            if (bv < 5.0e4f)   // assigned requires in_box (in-box cost << 5e4)
                atomicOr(&mask[(size_t)b * NN + bn], 1u << g);
        }
        __syncthreads();
    }
}

// ---- Kernel D: per-prediction losses -> per-block partials ---------------
__global__ void kD(const float* __restrict__ pred, const float* __restrict__ tgt,
                   const float* __restrict__ objlogit,
                   const unsigned int* __restrict__ mask,
                   const float2* __restrict__ cv2, float* __restrict__ partials) {
    int i = blockIdx.x * 256 + threadIdx.x;
    float obj_l = 0.0f, cls_l = 0.0f, reg_l = 0.0f, nfg = 0.0f;
    if (i < BB * NN) {
        int b = i / NN;
        unsigned int mk = mask[i];
        float fg = mk ? 1.0f : 0.0f;
        obj_l = bcef_(objlogit[i], fg);
        if (mk) {
            nfg = 1.0f;
            float best = 3.0e30f;
            int bg = 0;
            for (int g = 0; g < MM; ++g) {
                if ((mk >> g) & 1u) {
                    float cvv = cv2[(size_t)i * MM + g].x;
                    if (cvv < best) { best = cvv; bg = g; }  // first-min tie rule
                }
            }
            const float* p = pred + (size_t)i * PD;
            const float* t = tgt + ((size_t)b * MM + bg) * 5;
            int gcls = (int)t[0];
            for (int c = 0; c < NC; ++c)
                cls_l += bcef_(p[5 + c], (c == gcls) ? 1.0f : 0.0f);
            float cx = p[0], cy = p[1], w = p[2], h = p[3];
            float px1 = cx - w * 0.5f, py1 = cy - h * 0.5f;
            float px2 = cx + w * 0.5f, py2 = cy + h * 0.5f;
            float tx1 = t[1] - t[3] * 0.5f, ty1 = t[2] - t[4] * 0.5f;
            float tx2 = t[1] + t[3] * 0.5f, ty2 = t[2] + t[4] * 0.5f;
            float ix1 = fmaxf(px1, tx1), iy1 = fmaxf(py1, ty1);
            float ix2 = fminf(px2, tx2), iy2 = fminf(py2, ty2);
            float inter = fmaxf(ix2 - ix1, 0.0f) * fmaxf(iy2 - iy1, 0.0f);
            float pa = fmaxf(px2 - px1, 0.0f) * fmaxf(py2 - py1, 0.0f);
            float ta = fmaxf(tx2 - tx1, 0.0f) * fmaxf(ty2 - ty1, 0.0f);
            float uni = pa + ta - inter + 1e-7f;
            float iou = inter / uni;
            float ex1 = fminf(px1, tx1), ey1 = fminf(py1, ty1);
            float ex2 = fmaxf(px2, tx2), ey2 = fmaxf(py2, ty2);
            float enclose = (ex2 - ex1) * (ey2 - ey1) + 1e-7f;
            float giou = iou - (enclose - uni) / enclose;
            reg_l = 1.0f - giou;
        }
    }
    __shared__ float red[256];
    float sums[4] = {cls_l, obj_l, reg_l, nfg};
    float out4[4];
    for (int j = 0; j < 4; ++j) {
        red[threadIdx.x] = sums[j];
        __syncthreads();
        for (int off = 128; off > 0; off >>= 1) {
            if (threadIdx.x < off) red[threadIdx.x] += red[threadIdx.x + off];
            __syncthreads();
        }
        out4[j] = red[0];
        __syncthreads();
    }
    if (threadIdx.x == 0) {
        float* pr = partials + (size_t)blockIdx.x * 4;
        pr[0] = out4[0]; pr[1] = out4[1]; pr[2] = out4[2]; pr[3] = out4[3];
    }
}

// ---- Kernel E: final deterministic reduction -----------------------------
__global__ void kE(const float* __restrict__ partials, int nblk, float* __restrict__ out) {
    __shared__ float red[256];
    float s[4] = {0, 0, 0, 0};
    for (int i = threadIdx.x; i < nblk; i += 256) {
        s[0] += partials[(size_t)i * 4 + 0];
        s[1] += partials[(size_t)i * 4 + 1];
        s[2] += partials[(size_t)i * 4 + 2];
        s[3] += partials[(size_t)i * 4 + 3];
    }
    float tot[4];
    for (int j = 0; j < 4; ++j) {
        red[threadIdx.x] = s[j];
        __syncthreads();
        for (int off = 128; off > 0; off >>= 1) {
            if (threadIdx.x < off) red[threadIdx.x] += red[threadIdx.x + off];
            __syncthreads();
        }
        tot[j] = red[0];
        __syncthreads();
    }
    if (threadIdx.x == 0) {
        float nfg = fmaxf(tot[3], 1.0f);
        out[0] = (tot[0] + tot[1] + 5.0f * tot[2]) / nfg;
    }
}

extern "C" void kernel_launch(void* const* d_in, const int* in_sizes, int n_in,
                              void* d_out, int out_size, void* d_ws, size_t ws_size,
                              hipStream_t stream) {
    const float* pred = (const float*)d_in[0];   // (B, N, 85) f32
    const float* tgt  = (const float*)d_in[1];   // (B, M, 5)  f32
    float* out = (float*)d_out;

    // Workspace layout (~78 MB)
    char* ws = (char*)d_ws;
    size_t off = 0;
    float2* cv2 = (float2*)(ws + off);              off += (size_t)BB * NN * MM * sizeof(float2);
    unsigned int* mask = (unsigned int*)(ws + off); off += (size_t)BB * NN * sizeof(unsigned int);
    float* objlogit = (float*)(ws + off);           off += (size_t)BB * NN * sizeof(float);
    float* piou = (float*)(ws + off);               off += (size_t)BB * NCHUNK * MM * TOPK * sizeof(float);
    float2* pcvn = (float2*)(ws + off);             off += (size_t)BB * NCHUNK * MM * TOPK * sizeof(float2);
    float* partials = (float*)(ws + off);

    const int nblk = (BB * NN + 255) / 256;  // 1050

    // mask accumulates via atomicOr -> zero every call
    hipMemsetAsync(mask, 0, (size_t)BB * NN * sizeof(unsigned int), stream);

    kAB<<<2048, 256, 0, stream>>>(pred, tgt, objlogit, cv2);

    dim3 gC1(NCHUNK, BB);                    // 56 x 32 = 1792 blocks
    kC1<<<gC1, 256, 0, stream>>>(cv2, piou, pcvn);

    dim3 gC2(MM, BB);                        // 32 x 32
    kC2<<<gC2, 64, 0, stream>>>(piou, pcvn, mask);

    kD<<<nblk, 256, 0, stream>>>(pred, tgt, objlogit, mask, cv2, partials);

    kE<<<1, 256, 0, stream>>>(partials, nblk, out);
}

// Round 6
// 313.191 us; speedup vs baseline: 3.0593x; 3.0593x over previous
//
#include <hip/hip_runtime.h>
#include <math.h>

#define BB 32
#define NN 8400
#define MM 32
#define NC 80
#define PD 85
#define TOPK 10
#define FLT_BIG 3.4e38f

__device__ __forceinline__ float sigmoidf_(float x) { return 1.0f / (1.0f + expf(-x)); }
__device__ __forceinline__ float bcef_(float x, float t) {
    return fmaxf(x, 0.0f) - x * t + log1pf(expf(-fabsf(x)));
}

// ---- Kernel AB: wave-per-2-rows, zero LDS, fully coalesced ----------------
// (unchanged from round 4/5 — passing and fast)
__global__ void __launch_bounds__(256) kAB(const float* __restrict__ pred,
                                           const float* __restrict__ tgt,
                                           float* __restrict__ objlogit,
                                           float2* __restrict__ cv2) {
    const int lane = threadIdx.x & 63;
    const int gw = blockIdx.x * (blockDim.x >> 6) + (threadIdx.x >> 6);
    const int nw = gridDim.x * (blockDim.x >> 6);
    const int rs = lane >> 5, g = lane & 31;
    const int NPAIR = BB * (NN / 2);

    for (int pair = gw; pair < NPAIR; pair += nw) {
        const int b = pair / (NN / 2);
        const int r0 = (pair - b * (NN / 2)) * 2;
        const size_t off = ((size_t)b * NN + r0) * PD;
        float x0 = pred[off + lane];                       // pos 0..63
        float x1 = pred[off + 64 + lane];                  // pos 64..127
        float x2 = (lane < 42) ? pred[off + 128 + lane] : 0.0f; // pos 128..169

        // row headers: row0 pos 0..4, row1 pos 85..89
        float cx0 = __shfl(x0, 0), cy0 = __shfl(x0, 1), w0 = __shfl(x0, 2), h0 = __shfl(x0, 3), ol0 = __shfl(x0, 4);
        float cx1 = __shfl(x1, 21), cy1 = __shfl(x1, 22), w1 = __shfl(x1, 23), h1 = __shfl(x1, 24), ol1 = __shfl(x1, 25);
        float so0 = sigmoidf_(ol0), so1 = sigmoidf_(ol1);
        if (lane == 0) objlogit[(size_t)b * NN + r0] = ol0;
        else if (lane == 1) objlogit[(size_t)b * NN + r0 + 1] = ol1;

        // class lq terms distributed one-per-lane
        float a0 = 0.0f, a1 = 0.0f;
        if (lane >= 5)  a0 += logf(1.0f - sqrtf(sigmoidf_(x0) * so0) + 1e-7f);
        if (lane < 21)  a0 += logf(1.0f - sqrtf(sigmoidf_(x1) * so0) + 1e-7f);
        if (lane >= 26) a1 += logf(1.0f - sqrtf(sigmoidf_(x1) * so1) + 1e-7f);
        if (lane < 42)  a1 += logf(1.0f - sqrtf(sigmoidf_(x2) * so1) + 1e-7f);
        #pragma unroll
        for (int o = 32; o; o >>= 1) { a0 += __shfl_xor(a0, o); a1 += __shfl_xor(a1, o); }
        float base0 = -a0, base1 = -a1;

        float cxs = rs ? cx1 : cx0, cys = rs ? cy1 : cy0;
        float ws_ = rs ? w1 : w0, hs_ = rs ? h1 : h0;
        float sos = rs ? so1 : so0, bases = rs ? base1 : base0;
        float px1 = cxs - ws_ * 0.5f, py1 = cys - hs_ * 0.5f;
        float px2 = cxs + ws_ * 0.5f, py2 = cys + hs_ * 0.5f;
        float pa = fmaxf(px2 - px1, 0.0f) * fmaxf(py2 - py1, 0.0f);

        const float* t = tgt + ((size_t)b * MM + g) * 5;
        int gcls = (int)t[0];
        float gx1 = t[1] - t[3] * 0.5f, gy1 = t[2] - t[4] * 0.5f;
        float gx2 = t[1] + t[3] * 0.5f, gy2 = t[2] + t[4] * 0.5f;
        float ga = fmaxf(gx2 - gx1, 0.0f) * fmaxf(gy2 - gy1, 0.0f);

        int posn = rs * 85 + 5 + gcls;
        int k = posn >> 6, ls = posn & 63;
        float g0 = __shfl(x0, ls), g1 = __shfl(x1, ls), g2 = __shfl(x2, ls);
        float cl = (k == 0) ? g0 : ((k == 1) ? g1 : g2);

        float ix1 = fmaxf(gx1, px1), iy1 = fmaxf(gy1, py1);
        float ix2 = fminf(gx2, px2), iy2 = fminf(gy2, py2);
        float inter = fmaxf(ix2 - ix1, 0.0f) * fmaxf(iy2 - iy1, 0.0f);
        float uni = ga + pa - inter + 1e-7f;
        float iou = inter / uni;
        bool inb = (cxs > gx1) && (cxs < gx2) && (cys > gy1) && (cys < gy2);
        float s = sqrtf(sigmoidf_(cl) * sos);
        float lp = logf(s + 1e-7f);
        float lq = logf(1.0f - s + 1e-7f);
        float cc = bases - lp + lq;
        float co = cc + 3.0f * (-logf(iou + 1e-8f)) + (inb ? 0.0f : 100000.0f);

        cv2[((size_t)b * NN + r0) * MM + lane] = make_float2(co, inb ? iou : 0.0f);
    }
}

// ---- Kernel C: per-(b,g) dyn_k + assignment (round-3 proven structure) ----
// Reads interleaved cv2 [b][n][g]: one 8B load per element (cost+viou).
__global__ void __launch_bounds__(256) kC(const float2* __restrict__ cv2,
                                          unsigned int* __restrict__ mask) {
    const int g = blockIdx.x, b = blockIdx.y, tid = threadIdx.x;
    const int wid = tid >> 6, lane = tid & 63;
    const float2* cvb = cv2 + (size_t)b * NN * MM + g;

    // per-thread candidate lists (registers, static indexing only)
    float ti[TOPK];                 // top ious, descending
    float cv[TOPK]; int ci[TOPK];   // smallest costs, lex (v, idx) ascending
    #pragma unroll
    for (int j = 0; j < TOPK; ++j) { ti[j] = -1.0f; cv[j] = FLT_BIG; ci[j] = 0x7fffffff; }

    for (int n = tid; n < NN; n += 256) {
        float2 e = cvb[(size_t)n * MM];
        float c = e.x, v = e.y;
        if (v > ti[TOPK - 1]) {
            ti[TOPK - 1] = v;
            #pragma unroll
            for (int j = TOPK - 1; j > 0; --j)
                if (ti[j] > ti[j - 1]) { float tmp = ti[j - 1]; ti[j - 1] = ti[j]; ti[j] = tmp; }
        }
        // per-thread scan order is increasing n -> strict < keeps stable (v, idx)
        if (c < cv[TOPK - 1]) {
            cv[TOPK - 1] = c; ci[TOPK - 1] = n;
            #pragma unroll
            for (int j = TOPK - 1; j > 0; --j)
                if (cv[j] < cv[j - 1]) {
                    float tv = cv[j - 1]; cv[j - 1] = cv[j]; cv[j] = tv;
                    int tn = ci[j - 1]; ci[j - 1] = ci[j]; ci[j] = tn;
                }
        }
    }

    __shared__ float lv[256 * TOPK];
    __shared__ int   li[256 * TOPK];
    __shared__ float wv[4]; __shared__ int wn[4], wp[4];
    __shared__ float s_sum; __shared__ int s_dynk;

    // ---- Phase 1 merge: sum of global top-10 ious (descending add order) --
    #pragma unroll
    for (int j = 0; j < TOPK; ++j) lv[tid + 256 * j] = ti[j];
    __syncthreads();
    for (int p = 0; p < TOPK; ++p) {
        float bv = -2.0f; int bp = -1;
        #pragma unroll
        for (int j = 0; j < TOPK; ++j) {
            int idx = tid + 256 * j; float v = lv[idx];
            if (v > bv) { bv = v; bp = idx; }
        }
        for (int off = 32; off; off >>= 1) {
            float ov = __shfl_xor(bv, off); int op = __shfl_xor(bp, off);
            if (ov > bv || (ov == bv && op < bp)) { bv = ov; bp = op; }
        }
        if (lane == 0) { wv[wid] = bv; wp[wid] = bp; }
        __syncthreads();
        if (tid == 0) {
            float mb = wv[0]; int mp = wp[0];
            for (int w2 = 1; w2 < 4; ++w2)
                if (wv[w2] > mb || (wv[w2] == mb && wp[w2] < mp)) { mb = wv[w2]; mp = wp[w2]; }
            s_sum = (p == 0) ? mb : (s_sum + mb);
            lv[mp] = -2.0f;
        }
        __syncthreads();
    }
    if (tid == 0) {
        int k = (int)s_sum;          // trunc toward zero, sum >= 0
        if (k < 1) k = 1;
        if (k > TOPK) k = TOPK;
        s_dynk = k;
    }

    // ---- Phase 2 merge: dyn_k lexicographically-smallest (cost, idx) ------
    #pragma unroll
    for (int j = 0; j < TOPK; ++j) { lv[tid + 256 * j] = cv[j]; li[tid + 256 * j] = ci[j]; }
    __syncthreads();
    const int dynk = s_dynk;
    for (int p = 0; p < dynk; ++p) {
        float bv = FLT_BIG; int bn = 0x7fffffff; int bp = -1;
        #pragma unroll
        for (int j = 0; j < TOPK; ++j) {
            int idx = tid + 256 * j; float v = lv[idx]; int nn2 = li[idx];
            if (v < bv || (v == bv && nn2 < bn)) { bv = v; bn = nn2; bp = idx; }
        }
        for (int off = 32; off; off >>= 1) {
            float ov = __shfl_xor(bv, off);
            int on = __shfl_xor(bn, off);
            int op = __shfl_xor(bp, off);
            if (ov < bv || (ov == bv && on < bn)) { bv = ov; bn = on; bp = op; }
        }
        if (lane == 0) { wv[wid] = bv; wn[wid] = bn; wp[wid] = bp; }
        __syncthreads();
        if (tid == 0) {
            float mb = wv[0]; int mn = wn[0], mp = wp[0];
            for (int w2 = 1; w2 < 4; ++w2)
                if (wv[w2] < mb || (wv[w2] == mb && wn[w2] < mn)) { mb = wv[w2]; mn = wn[w2]; mp = wp[w2]; }
            lv[mp] = FLT_BIG; li[mp] = 0x7fffffff;
            if (mb < 5.0e4f)  // assigned requires in_box (in-box cost << 5e4)
                atomicOr(&mask[(size_t)b * NN + mn], 1u << g);
        }
        __syncthreads();
    }
}

// ---- Kernel D: per-prediction losses -> per-block partials ---------------
__global__ void kD(const float* __restrict__ pred, const float* __restrict__ tgt,
                   const float* __restrict__ objlogit,
                   const unsigned int* __restrict__ mask,
                   const float2* __restrict__ cv2, float* __restrict__ partials) {
    int i = blockIdx.x * 256 + threadIdx.x;
    float obj_l = 0.0f, cls_l = 0.0f, reg_l = 0.0f, nfg = 0.0f;
    if (i < BB * NN) {
        int b = i / NN;
        unsigned int mk = mask[i];
        float fg = mk ? 1.0f : 0.0f;
        obj_l = bcef_(objlogit[i], fg);
        if (mk) {
            nfg = 1.0f;
            float best = 3.0e30f;
            int bg = 0;
            for (int g = 0; g < MM; ++g) {
                if ((mk >> g) & 1u) {
                    float cvv = cv2[(size_t)i * MM + g].x;
                    if (cvv < best) { best = cvv; bg = g; }  // first-min tie rule
                }
            }
            const float* p = pred + (size_t)i * PD;
            const float* t = tgt + ((size_t)b * MM + bg) * 5;
            int gcls = (int)t[0];
            for (int c = 0; c < NC; ++c)
                cls_l += bcef_(p[5 + c], (c == gcls) ? 1.0f : 0.0f);
            float cx = p[0], cy = p[1], w = p[2], h = p[3];
            float px1 = cx - w * 0.5f, py1 = cy - h * 0.5f;
            float px2 = cx + w * 0.5f, py2 = cy + h * 0.5f;
            float tx1 = t[1] - t[3] * 0.5f, ty1 = t[2] - t[4] * 0.5f;
            float tx2 = t[1] + t[3] * 0.5f, ty2 = t[2] + t[4] * 0.5f;
            float ix1 = fmaxf(px1, tx1), iy1 = fmaxf(py1, ty1);
            float ix2 = fminf(px2, tx2), iy2 = fminf(py2, ty2);
            float inter = fmaxf(ix2 - ix1, 0.0f) * fmaxf(iy2 - iy1, 0.0f);
            float pa = fmaxf(px2 - px1, 0.0f) * fmaxf(py2 - py1, 0.0f);
            float ta = fmaxf(tx2 - tx1, 0.0f) * fmaxf(ty2 - ty1, 0.0f);
            float uni = pa + ta - inter + 1e-7f;
            float iou = inter / uni;
            float ex1 = fminf(px1, tx1), ey1 = fminf(py1, ty1);
            float ex2 = fmaxf(px2, tx2), ey2 = fmaxf(py2, ty2);
            float enclose = (ex2 - ex1) * (ey2 - ey1) + 1e-7f;
            float giou = iou - (enclose - uni) / enclose;
            reg_l = 1.0f - giou;
        }
    }
    __shared__ float red[256];
    float sums[4] = {cls_l, obj_l, reg_l, nfg};
    float out4[4];
    for (int j = 0; j < 4; ++j) {
        red[threadIdx.x] = sums[j];
        __syncthreads();
        for (int off = 128; off > 0; off >>= 1) {
            if (threadIdx.x < off) red[threadIdx.x] += red[threadIdx.x + off];
            __syncthreads();
        }
        out4[j] = red[0];
        __syncthreads();
    }
    if (threadIdx.x == 0) {
        float* pr = partials + (size_t)blockIdx.x * 4;
        pr[0] = out4[0]; pr[1] = out4[1]; pr[2] = out4[2]; pr[3] = out4[3];
    }
}

// ---- Kernel E: final deterministic reduction -----------------------------
__global__ void kE(const float* __restrict__ partials, int nblk, float* __restrict__ out) {
    __shared__ float red[256];
    float s[4] = {0, 0, 0, 0};
    for (int i = threadIdx.x; i < nblk; i += 256) {
        s[0] += partials[(size_t)i * 4 + 0];
        s[1] += partials[(size_t)i * 4 + 1];
        s[2] += partials[(size_t)i * 4 + 2];
        s[3] += partials[(size_t)i * 4 + 3];
    }
    float tot[4];
    for (int j = 0; j < 4; ++j) {
        red[threadIdx.x] = s[j];
        __syncthreads();
        for (int off = 128; off > 0; off >>= 1) {
            if (threadIdx.x < off) red[threadIdx.x] += red[threadIdx.x + off];
            __syncthreads();
        }
        tot[j] = red[0];
        __syncthreads();
    }
    if (threadIdx.x == 0) {
        float nfg = fmaxf(tot[3], 1.0f);
        out[0] = (tot[0] + tot[1] + 5.0f * tot[2]) / nfg;
    }
}

extern "C" void kernel_launch(void* const* d_in, const int* in_sizes, int n_in,
                              void* d_out, int out_size, void* d_ws, size_t ws_size,
                              hipStream_t stream) {
    const float* pred = (const float*)d_in[0];   // (B, N, 85) f32
    const float* tgt  = (const float*)d_in[1];   // (B, M, 5)  f32
    float* out = (float*)d_out;

    // Workspace layout (~71 MB)
    char* ws = (char*)d_ws;
    size_t off = 0;
    float2* cv2 = (float2*)(ws + off);              off += (size_t)BB * NN * MM * sizeof(float2);
    unsigned int* mask = (unsigned int*)(ws + off); off += (size_t)BB * NN * sizeof(unsigned int);
    float* objlogit = (float*)(ws + off);           off += (size_t)BB * NN * sizeof(float);
    float* partials = (float*)(ws + off);

    const int nblk = (BB * NN + 255) / 256;  // 1050

    // mask accumulates via atomicOr -> zero every call
    hipMemsetAsync(mask, 0, (size_t)BB * NN * sizeof(unsigned int), stream);

    kAB<<<2048, 256, 0, stream>>>(pred, tgt, objlogit, cv2);

    dim3 gC(MM, BB);                         // 32 x 32 = 1024 blocks
    kC<<<gC, 256, 0, stream>>>(cv2, mask);

    kD<<<nblk, 256, 0, stream>>>(pred, tgt, objlogit, mask, cv2, partials);

    kE<<<1, 256, 0, stream>>>(partials, nblk, out);
}

// Round 7
// 213.871 us; speedup vs baseline: 4.4800x; 1.4644x over previous
//
#include <hip/hip_runtime.h>
#include <math.h>

#define BB 32
#define NN 8400
#define MM 32
#define NC 80
#define PD 85
#define TOPK 10
#define FLT_BIG 3.4e38f

__device__ __forceinline__ float sigmoidf_(float x) { return 1.0f / (1.0f + expf(-x)); }
__device__ __forceinline__ float bcef_(float x, float t) {
    return fmaxf(x, 0.0f) - x * t + log1pf(expf(-fabsf(x)));
}

// ---- Kernel AB: wave-per-2-rows, zero LDS, fully coalesced ----------------
// (unchanged — proven)
__global__ void __launch_bounds__(256) kAB(const float* __restrict__ pred,
                                           const float* __restrict__ tgt,
                                           float* __restrict__ objlogit,
                                           float2* __restrict__ cv2) {
    const int lane = threadIdx.x & 63;
    const int gw = blockIdx.x * (blockDim.x >> 6) + (threadIdx.x >> 6);
    const int nw = gridDim.x * (blockDim.x >> 6);
    const int rs = lane >> 5, g = lane & 31;
    const int NPAIR = BB * (NN / 2);

    for (int pair = gw; pair < NPAIR; pair += nw) {
        const int b = pair / (NN / 2);
        const int r0 = (pair - b * (NN / 2)) * 2;
        const size_t off = ((size_t)b * NN + r0) * PD;
        float x0 = pred[off + lane];                       // pos 0..63
        float x1 = pred[off + 64 + lane];                  // pos 64..127
        float x2 = (lane < 42) ? pred[off + 128 + lane] : 0.0f; // pos 128..169

        float cx0 = __shfl(x0, 0), cy0 = __shfl(x0, 1), w0 = __shfl(x0, 2), h0 = __shfl(x0, 3), ol0 = __shfl(x0, 4);
        float cx1 = __shfl(x1, 21), cy1 = __shfl(x1, 22), w1 = __shfl(x1, 23), h1 = __shfl(x1, 24), ol1 = __shfl(x1, 25);
        float so0 = sigmoidf_(ol0), so1 = sigmoidf_(ol1);
        if (lane == 0) objlogit[(size_t)b * NN + r0] = ol0;
        else if (lane == 1) objlogit[(size_t)b * NN + r0 + 1] = ol1;

        float a0 = 0.0f, a1 = 0.0f;
        if (lane >= 5)  a0 += logf(1.0f - sqrtf(sigmoidf_(x0) * so0) + 1e-7f);
        if (lane < 21)  a0 += logf(1.0f - sqrtf(sigmoidf_(x1) * so0) + 1e-7f);
        if (lane >= 26) a1 += logf(1.0f - sqrtf(sigmoidf_(x1) * so1) + 1e-7f);
        if (lane < 42)  a1 += logf(1.0f - sqrtf(sigmoidf_(x2) * so1) + 1e-7f);
        #pragma unroll
        for (int o = 32; o; o >>= 1) { a0 += __shfl_xor(a0, o); a1 += __shfl_xor(a1, o); }
        float base0 = -a0, base1 = -a1;

        float cxs = rs ? cx1 : cx0, cys = rs ? cy1 : cy0;
        float ws_ = rs ? w1 : w0, hs_ = rs ? h1 : h0;
        float sos = rs ? so1 : so0, bases = rs ? base1 : base0;
        float px1 = cxs - ws_ * 0.5f, py1 = cys - hs_ * 0.5f;
        float px2 = cxs + ws_ * 0.5f, py2 = cys + hs_ * 0.5f;
        float pa = fmaxf(px2 - px1, 0.0f) * fmaxf(py2 - py1, 0.0f);

        const float* t = tgt + ((size_t)b * MM + g) * 5;
        int gcls = (int)t[0];
        float gx1 = t[1] - t[3] * 0.5f, gy1 = t[2] - t[4] * 0.5f;
        float gx2 = t[1] + t[3] * 0.5f, gy2 = t[2] + t[4] * 0.5f;
        float ga = fmaxf(gx2 - gx1, 0.0f) * fmaxf(gy2 - gy1, 0.0f);

        int posn = rs * 85 + 5 + gcls;
        int k = posn >> 6, ls = posn & 63;
        float g0 = __shfl(x0, ls), g1 = __shfl(x1, ls), g2 = __shfl(x2, ls);
        float cl = (k == 0) ? g0 : ((k == 1) ? g1 : g2);

        float ix1 = fmaxf(gx1, px1), iy1 = fmaxf(gy1, py1);
        float ix2 = fminf(gx2, px2), iy2 = fminf(gy2, py2);
        float inter = fmaxf(ix2 - ix1, 0.0f) * fmaxf(iy2 - iy1, 0.0f);
        float uni = ga + pa - inter + 1e-7f;
        float iou = inter / uni;
        bool inb = (cxs > gx1) && (cxs < gx2) && (cys > gy1) && (cys < gy2);
        float s = sqrtf(sigmoidf_(cl) * sos);
        float lp = logf(s + 1e-7f);
        float lq = logf(1.0f - s + 1e-7f);
        float cc = bases - lp + lq;
        float co = cc + 3.0f * (-logf(iou + 1e-8f)) + (inb ? 0.0f : 100000.0f);

        cv2[((size_t)b * NN + r0) * MM + lane] = make_float2(co, inb ? iou : 0.0f);
    }
}

// ---- Kernel C: per-(b,g) dyn_k + assignment (unchanged) -------------------
__global__ void __launch_bounds__(256) kC(const float2* __restrict__ cv2,
                                          unsigned int* __restrict__ mask) {
    const int g = blockIdx.x, b = blockIdx.y, tid = threadIdx.x;
    const int wid = tid >> 6, lane = tid & 63;
    const float2* cvb = cv2 + (size_t)b * NN * MM + g;

    float ti[TOPK];
    float cv[TOPK]; int ci[TOPK];
    #pragma unroll
    for (int j = 0; j < TOPK; ++j) { ti[j] = -1.0f; cv[j] = FLT_BIG; ci[j] = 0x7fffffff; }

    for (int n = tid; n < NN; n += 256) {
        float2 e = cvb[(size_t)n * MM];
        float c = e.x, v = e.y;
        if (v > ti[TOPK - 1]) {
            ti[TOPK - 1] = v;
            #pragma unroll
            for (int j = TOPK - 1; j > 0; --j)
                if (ti[j] > ti[j - 1]) { float tmp = ti[j - 1]; ti[j - 1] = ti[j]; ti[j] = tmp; }
        }
        if (c < cv[TOPK - 1]) {
            cv[TOPK - 1] = c; ci[TOPK - 1] = n;
            #pragma unroll
            for (int j = TOPK - 1; j > 0; --j)
                if (cv[j] < cv[j - 1]) {
                    float tv = cv[j - 1]; cv[j - 1] = cv[j]; cv[j] = tv;
                    int tn = ci[j - 1]; ci[j - 1] = ci[j]; ci[j] = tn;
                }
        }
    }

    __shared__ float lv[256 * TOPK];
    __shared__ int   li[256 * TOPK];
    __shared__ float wv[4]; __shared__ int wn[4], wp[4];
    __shared__ float s_sum; __shared__ int s_dynk;

    #pragma unroll
    for (int j = 0; j < TOPK; ++j) lv[tid + 256 * j] = ti[j];
    __syncthreads();
    for (int p = 0; p < TOPK; ++p) {
        float bv = -2.0f; int bp = -1;
        #pragma unroll
        for (int j = 0; j < TOPK; ++j) {
            int idx = tid + 256 * j; float v = lv[idx];
            if (v > bv) { bv = v; bp = idx; }
        }
        for (int off = 32; off; off >>= 1) {
            float ov = __shfl_xor(bv, off); int op = __shfl_xor(bp, off);
            if (ov > bv || (ov == bv && op < bp)) { bv = ov; bp = op; }
        }
        if (lane == 0) { wv[wid] = bv; wp[wid] = bp; }
        __syncthreads();
        if (tid == 0) {
            float mb = wv[0]; int mp = wp[0];
            for (int w2 = 1; w2 < 4; ++w2)
                if (wv[w2] > mb || (wv[w2] == mb && wp[w2] < mp)) { mb = wv[w2]; mp = wp[w2]; }
            s_sum = (p == 0) ? mb : (s_sum + mb);
            lv[mp] = -2.0f;
        }
        __syncthreads();
    }
    if (tid == 0) {
        int k = (int)s_sum;
        if (k < 1) k = 1;
        if (k > TOPK) k = TOPK;
        s_dynk = k;
    }

    #pragma unroll
    for (int j = 0; j < TOPK; ++j) { lv[tid + 256 * j] = cv[j]; li[tid + 256 * j] = ci[j]; }
    __syncthreads();
    const int dynk = s_dynk;
    for (int p = 0; p < dynk; ++p) {
        float bv = FLT_BIG; int bn = 0x7fffffff; int bp = -1;
        #pragma unroll
        for (int j = 0; j < TOPK; ++j) {
            int idx = tid + 256 * j; float v = lv[idx]; int nn2 = li[idx];
            if (v < bv || (v == bv && nn2 < bn)) { bv = v; bn = nn2; bp = idx; }
        }
        for (int off = 32; off; off >>= 1) {
            float ov = __shfl_xor(bv, off);
            int on = __shfl_xor(bn, off);
            int op = __shfl_xor(bp, off);
            if (ov < bv || (ov == bv && on < bn)) { bv = ov; bn = on; bp = op; }
        }
        if (lane == 0) { wv[wid] = bv; wn[wid] = bn; wp[wid] = bp; }
        __syncthreads();
        if (tid == 0) {
            float mb = wv[0]; int mn = wn[0], mp = wp[0];
            for (int w2 = 1; w2 < 4; ++w2)
                if (wv[w2] < mb || (wv[w2] == mb && wn[w2] < mn)) { mb = wv[w2]; mn = wn[w2]; mp = wp[w2]; }
            lv[mp] = FLT_BIG; li[mp] = 0x7fffffff;
            if (mb < 5.0e4f)
                atomicOr(&mask[(size_t)b * NN + mn], 1u << g);
        }
        __syncthreads();
    }
}

// ---- Kernel D: compacted fg, item-parallel class BCE ----------------------
// Fg threads are ballot-compacted (deterministic, ordered by tid); the 80-class
// BCE runs as a flat item loop over cnt*80 items shared by all 256 threads,
// removing the exec-masked 80-deep serial transcendental chain from every wave.
__global__ void __launch_bounds__(256) kD(const float* __restrict__ pred,
                   const float* __restrict__ tgt,
                   const float* __restrict__ objlogit,
                   const unsigned int* __restrict__ mask,
                   const float2* __restrict__ cv2, float* __restrict__ partials) {
    const int tid = threadIdx.x;
    const int i0 = blockIdx.x * 256;
    const int i = i0 + tid;                 // BB*NN == 1050*256 exactly
    const int lane = tid & 63, wid = tid >> 6;
    const int b = i / NN;

    float obj_l, cls_l = 0.0f, reg_l = 0.0f, nfg = 0.0f;
    const unsigned int mk = mask[i];
    obj_l = bcef_(objlogit[i], mk ? 1.0f : 0.0f);

    __shared__ int s_list[256];   // block-local tid of e-th fg entry
    __shared__ int s_gcls[256];   // its matched gt class
    __shared__ int s_wbase[4];
    __shared__ int s_cnt;

    // deterministic compaction: wave ballot + popcount prefix
    unsigned long long bal = __ballot(mk != 0);
    int wpos = __popcll(bal & ((1ull << lane) - 1ull));
    if (lane == 0) s_wbase[wid] = __popcll(bal);
    __syncthreads();
    if (tid == 0) {
        int acc = 0;
        for (int w = 0; w < 4; ++w) { int t_ = s_wbase[w]; s_wbase[w] = acc; acc += t_; }
        s_cnt = acc;
    }
    __syncthreads();

    if (mk) {
        int e = s_wbase[wid] + wpos;
        s_list[e] = tid;
        nfg = 1.0f;
        // matched gt: first-min over set bits
        float best = 3.0e30f; int bg = 0;
        for (int g = 0; g < MM; ++g) {
            if ((mk >> g) & 1u) {
                float cvv = cv2[(size_t)i * MM + g].x;
                if (cvv < best) { best = cvv; bg = g; }
            }
        }
        const float* t = tgt + ((size_t)b * MM + bg) * 5;
        s_gcls[e] = (int)t[0];
        // giou
        const float* p = pred + (size_t)i * PD;
        float cx = p[0], cy = p[1], w = p[2], h = p[3];
        float px1 = cx - w * 0.5f, py1 = cy - h * 0.5f;
        float px2 = cx + w * 0.5f, py2 = cy + h * 0.5f;
        float tx1 = t[1] - t[3] * 0.5f, ty1 = t[2] - t[4] * 0.5f;
        float tx2 = t[1] + t[3] * 0.5f, ty2 = t[2] + t[4] * 0.5f;
        float ix1 = fmaxf(px1, tx1), iy1 = fmaxf(py1, ty1);
        float ix2 = fminf(px2, tx2), iy2 = fminf(py2, ty2);
        float inter = fmaxf(ix2 - ix1, 0.0f) * fmaxf(iy2 - iy1, 0.0f);
        float pa = fmaxf(px2 - px1, 0.0f) * fmaxf(py2 - py1, 0.0f);
        float ta = fmaxf(tx2 - tx1, 0.0f) * fmaxf(ty2 - ty1, 0.0f);
        float uni = pa + ta - inter + 1e-7f;
        float iou = inter / uni;
        float ex1 = fminf(px1, tx1), ey1 = fminf(py1, ty1);
        float ex2 = fmaxf(px2, tx2), ey2 = fmaxf(py2, ty2);
        float enclose = (ex2 - ex1) * (ey2 - ey1) + 1e-7f;
        float giou = iou - (enclose - uni) / enclose;
        reg_l = 1.0f - giou;
    }
    __syncthreads();

    // item-parallel class BCE: item = e*80 + c, fixed thread assignment
    const int cnt = s_cnt;
    const int nitems = cnt * NC;
    for (int item = tid; item < nitems; item += 256) {
        int e = item / NC;
        int c = item - e * NC;
        int gi = i0 + s_list[e];
        float x = pred[(size_t)gi * PD + 5 + c];
        cls_l += bcef_(x, (c == s_gcls[e]) ? 1.0f : 0.0f);
    }

    __shared__ float red[256];
    float sums[4] = {cls_l, obj_l, reg_l, nfg};
    float out4[4];
    for (int j = 0; j < 4; ++j) {
        red[tid] = sums[j];
        __syncthreads();
        for (int off = 128; off > 0; off >>= 1) {
            if (tid < off) red[tid] += red[tid + off];
            __syncthreads();
        }
        out4[j] = red[0];
        __syncthreads();
    }
    if (tid == 0) {
        float* pr = partials + (size_t)blockIdx.x * 4;
        pr[0] = out4[0]; pr[1] = out4[1]; pr[2] = out4[2]; pr[3] = out4[3];
    }
}

// ---- Kernel E: final deterministic reduction -----------------------------
__global__ void kE(const float* __restrict__ partials, int nblk, float* __restrict__ out) {
    __shared__ float red[256];
    float s[4] = {0, 0, 0, 0};
    for (int i = threadIdx.x; i < nblk; i += 256) {
        s[0] += partials[(size_t)i * 4 + 0];
        s[1] += partials[(size_t)i * 4 + 1];
        s[2] += partials[(size_t)i * 4 + 2];
        s[3] += partials[(size_t)i * 4 + 3];
    }
    float tot[4];
    for (int j = 0; j < 4; ++j) {
        red[threadIdx.x] = s[j];
        __syncthreads();
        for (int off = 128; off > 0; off >>= 1) {
            if (threadIdx.x < off) red[threadIdx.x] += red[threadIdx.x + off];
            __syncthreads();
        }
        tot[j] = red[0];
        __syncthreads();
    }
    if (threadIdx.x == 0) {
        float nfg = fmaxf(tot[3], 1.0f);
        out[0] = (tot[0] + tot[1] + 5.0f * tot[2]) / nfg;
    }
}

extern "C" void kernel_launch(void* const* d_in, const int* in_sizes, int n_in,
                              void* d_out, int out_size, void* d_ws, size_t ws_size,
                              hipStream_t stream) {
    const float* pred = (const float*)d_in[0];   // (B, N, 85) f32
    const float* tgt  = (const float*)d_in[1];   // (B, M, 5)  f32
    float* out = (float*)d_out;

    // Workspace layout (~71 MB)
    char* ws = (char*)d_ws;
    size_t off = 0;
    float2* cv2 = (float2*)(ws + off);              off += (size_t)BB * NN * MM * sizeof(float2);
    unsigned int* mask = (unsigned int*)(ws + off); off += (size_t)BB * NN * sizeof(unsigned int);
    float* objlogit = (float*)(ws + off);           off += (size_t)BB * NN * sizeof(float);
    float* partials = (float*)(ws + off);

    const int nblk = (BB * NN + 255) / 256;  // 1050

    // mask accumulates via atomicOr -> zero every call
    hipMemsetAsync(mask, 0, (size_t)BB * NN * sizeof(unsigned int), stream);

    kAB<<<2048, 256, 0, stream>>>(pred, tgt, objlogit, cv2);

    dim3 gC(MM, BB);                         // 32 x 32 = 1024 blocks
    kC<<<gC, 256, 0, stream>>>(cv2, mask);

    kD<<<nblk, 256, 0, stream>>>(pred, tgt, objlogit, mask, cv2, partials);

    kE<<<1, 256, 0, stream>>>(partials, nblk, out);
}

// Round 8
// 176.997 us; speedup vs baseline: 5.4134x; 1.2083x over previous
//
#include <hip/hip_runtime.h>
#include <math.h>

#define BB 32
#define NN 8400
#define MM 32
#define NC 80
#define PD 85
#define TOPK 10
#define FLT_BIG 3.4e38f

__device__ __forceinline__ float sigmoidf_(float x) { return 1.0f / (1.0f + expf(-x)); }
__device__ __forceinline__ float bcef_(float x, float t) {
    return fmaxf(x, 0.0f) - x * t + log1pf(expf(-fabsf(x)));
}

// fast hardware-native helpers (kAB only): v_exp/v_log/v_rcp/v_sqrt, ~1-2 ulp
__device__ __forceinline__ float frcp_(float x)  { return __builtin_amdgcn_rcpf(x); }
__device__ __forceinline__ float fsqrt_(float x) { return __builtin_amdgcn_sqrtf(x); }
__device__ __forceinline__ float fsig_(float x)  { return frcp_(1.0f + __expf(-x)); }

// ---- Kernel AB: wave-per-2-rows, zero LDS, fully coalesced ----------------
// Same structure as round 6/7 (proven); transcendentals swapped to HW-native.
__global__ void __launch_bounds__(256) kAB(const float* __restrict__ pred,
                                           const float* __restrict__ tgt,
                                           float* __restrict__ objlogit,
                                           float2* __restrict__ cv2) {
    const int lane = threadIdx.x & 63;
    const int gw = blockIdx.x * (blockDim.x >> 6) + (threadIdx.x >> 6);
    const int nw = gridDim.x * (blockDim.x >> 6);
    const int rs = lane >> 5, g = lane & 31;
    const int NPAIR = BB * (NN / 2);

    for (int pair = gw; pair < NPAIR; pair += nw) {
        const int b = pair / (NN / 2);
        const int r0 = (pair - b * (NN / 2)) * 2;
        const size_t off = ((size_t)b * NN + r0) * PD;
        float x0 = pred[off + lane];                       // pos 0..63
        float x1 = pred[off + 64 + lane];                  // pos 64..127
        float x2 = (lane < 42) ? pred[off + 128 + lane] : 0.0f; // pos 128..169

        float cx0 = __shfl(x0, 0), cy0 = __shfl(x0, 1), w0 = __shfl(x0, 2), h0 = __shfl(x0, 3), ol0 = __shfl(x0, 4);
        float cx1 = __shfl(x1, 21), cy1 = __shfl(x1, 22), w1 = __shfl(x1, 23), h1 = __shfl(x1, 24), ol1 = __shfl(x1, 25);
        float so0 = fsig_(ol0), so1 = fsig_(ol1);
        if (lane == 0) objlogit[(size_t)b * NN + r0] = ol0;
        else if (lane == 1) objlogit[(size_t)b * NN + r0 + 1] = ol1;

        // class lq terms distributed one-per-lane (exec-masked regions)
        float a0 = 0.0f, a1 = 0.0f;
        if (lane >= 5)  a0 += __logf(1.0f - fsqrt_(fsig_(x0) * so0) + 1e-7f);
        if (lane < 21)  a0 += __logf(1.0f - fsqrt_(fsig_(x1) * so0) + 1e-7f);
        if (lane >= 26) a1 += __logf(1.0f - fsqrt_(fsig_(x1) * so1) + 1e-7f);
        if (lane < 42)  a1 += __logf(1.0f - fsqrt_(fsig_(x2) * so1) + 1e-7f);
        #pragma unroll
        for (int o = 32; o; o >>= 1) { a0 += __shfl_xor(a0, o); a1 += __shfl_xor(a1, o); }
        float base0 = -a0, base1 = -a1;

        float cxs = rs ? cx1 : cx0, cys = rs ? cy1 : cy0;
        float ws_ = rs ? w1 : w0, hs_ = rs ? h1 : h0;
        float sos = rs ? so1 : so0, bases = rs ? base1 : base0;
        float px1 = cxs - ws_ * 0.5f, py1 = cys - hs_ * 0.5f;
        float px2 = cxs + ws_ * 0.5f, py2 = cys + hs_ * 0.5f;
        float pa = fmaxf(px2 - px1, 0.0f) * fmaxf(py2 - py1, 0.0f);

        const float* t = tgt + ((size_t)b * MM + g) * 5;
        int gcls = (int)t[0];
        float gx1 = t[1] - t[3] * 0.5f, gy1 = t[2] - t[4] * 0.5f;
        float gx2 = t[1] + t[3] * 0.5f, gy2 = t[2] + t[4] * 0.5f;
        float ga = fmaxf(gx2 - gx1, 0.0f) * fmaxf(gy2 - gy1, 0.0f);

        int posn = rs * 85 + 5 + gcls;
        int k = posn >> 6, ls = posn & 63;
        float g0 = __shfl(x0, ls), g1 = __shfl(x1, ls), g2 = __shfl(x2, ls);
        float cl = (k == 0) ? g0 : ((k == 1) ? g1 : g2);

        float ix1 = fmaxf(gx1, px1), iy1 = fmaxf(gy1, py1);
        float ix2 = fminf(gx2, px2), iy2 = fminf(gy2, py2);
        float inter = fmaxf(ix2 - ix1, 0.0f) * fmaxf(iy2 - iy1, 0.0f);
        float uni = ga + pa - inter + 1e-7f;
        float iou = inter * frcp_(uni);
        bool inb = (cxs > gx1) && (cxs < gx2) && (cys > gy1) && (cys < gy2);
        float s = fsqrt_(fsig_(cl) * sos);
        float lp = __logf(s + 1e-7f);
        float lq = __logf(1.0f - s + 1e-7f);
        float cc = bases - lp + lq;
        float co = cc - 3.0f * __logf(iou + 1e-8f) + (inb ? 0.0f : 100000.0f);

        cv2[((size_t)b * NN + r0) * MM + lane] = make_float2(co, inb ? iou : 0.0f);
    }
}

// ---- Kernel C: per-(b,g) dyn_k + assignment (unchanged) -------------------
__global__ void __launch_bounds__(256) kC(const float2* __restrict__ cv2,
                                          unsigned int* __restrict__ mask) {
    const int g = blockIdx.x, b = blockIdx.y, tid = threadIdx.x;
    const int wid = tid >> 6, lane = tid & 63;
    const float2* cvb = cv2 + (size_t)b * NN * MM + g;

    float ti[TOPK];
    float cv[TOPK]; int ci[TOPK];
    #pragma unroll
    for (int j = 0; j < TOPK; ++j) { ti[j] = -1.0f; cv[j] = FLT_BIG; ci[j] = 0x7fffffff; }

    for (int n = tid; n < NN; n += 256) {
        float2 e = cvb[(size_t)n * MM];
        float c = e.x, v = e.y;
        if (v > ti[TOPK - 1]) {
            ti[TOPK - 1] = v;
            #pragma unroll
            for (int j = TOPK - 1; j > 0; --j)
                if (ti[j] > ti[j - 1]) { float tmp = ti[j - 1]; ti[j - 1] = ti[j]; ti[j] = tmp; }
        }
        if (c < cv[TOPK - 1]) {
            cv[TOPK - 1] = c; ci[TOPK - 1] = n;
            #pragma unroll
            for (int j = TOPK - 1; j > 0; --j)
                if (cv[j] < cv[j - 1]) {
                    float tv = cv[j - 1]; cv[j - 1] = cv[j]; cv[j] = tv;
                    int tn = ci[j - 1]; ci[j - 1] = ci[j]; ci[j] = tn;
                }
        }
    }

    __shared__ float lv[256 * TOPK];
    __shared__ int   li[256 * TOPK];
    __shared__ float wv[4]; __shared__ int wn[4], wp[4];
    __shared__ float s_sum; __shared__ int s_dynk;

    #pragma unroll
    for (int j = 0; j < TOPK; ++j) lv[tid + 256 * j] = ti[j];
    __syncthreads();
    for (int p = 0; p < TOPK; ++p) {
        float bv = -2.0f; int bp = -1;
        #pragma unroll
        for (int j = 0; j < TOPK; ++j) {
            int idx = tid + 256 * j; float v = lv[idx];
            if (v > bv) { bv = v; bp = idx; }
        }
        for (int off = 32; off; off >>= 1) {
            float ov = __shfl_xor(bv, off); int op = __shfl_xor(bp, off);
            if (ov > bv || (ov == bv && op < bp)) { bv = ov; bp = op; }
        }
        if (lane == 0) { wv[wid] = bv; wp[wid] = bp; }
        __syncthreads();
        if (tid == 0) {
            float mb = wv[0]; int mp = wp[0];
            for (int w2 = 1; w2 < 4; ++w2)
                if (wv[w2] > mb || (wv[w2] == mb && wp[w2] < mp)) { mb = wv[w2]; mp = wp[w2]; }
            s_sum = (p == 0) ? mb : (s_sum + mb);
            lv[mp] = -2.0f;
        }
        __syncthreads();
    }
    if (tid == 0) {
        int k = (int)s_sum;
        if (k < 1) k = 1;
        if (k > TOPK) k = TOPK;
        s_dynk = k;
    }

    #pragma unroll
    for (int j = 0; j < TOPK; ++j) { lv[tid + 256 * j] = cv[j]; li[tid + 256 * j] = ci[j]; }
    __syncthreads();
    const int dynk = s_dynk;
    for (int p = 0; p < dynk; ++p) {
        float bv = FLT_BIG; int bn = 0x7fffffff; int bp = -1;
        #pragma unroll
        for (int j = 0; j < TOPK; ++j) {
            int idx = tid + 256 * j; float v = lv[idx]; int nn2 = li[idx];
            if (v < bv || (v == bv && nn2 < bn)) { bv = v; bn = nn2; bp = idx; }
        }
        for (int off = 32; off; off >>= 1) {
            float ov = __shfl_xor(bv, off);
            int on = __shfl_xor(bn, off);
            int op = __shfl_xor(bp, off);
            if (ov < bv || (ov == bv && on < bn)) { bv = ov; bn = on; bp = op; }
        }
        if (lane == 0) { wv[wid] = bv; wn[wid] = bn; wp[wid] = bp; }
        __syncthreads();
        if (tid == 0) {
            float mb = wv[0]; int mn = wn[0], mp = wp[0];
            for (int w2 = 1; w2 < 4; ++w2)
                if (wv[w2] < mb || (wv[w2] == mb && wn[w2] < mn)) { mb = wv[w2]; mn = wn[w2]; mp = wp[w2]; }
            lv[mp] = FLT_BIG; li[mp] = 0x7fffffff;
            if (mb < 5.0e4f)
                atomicOr(&mask[(size_t)b * NN + mn], 1u << g);
        }
        __syncthreads();
    }
}

// ---- Kernel D: compacted fg, item-parallel class BCE (unchanged) ----------
__global__ void __launch_bounds__(256) kD(const float* __restrict__ pred,
                   const float* __restrict__ tgt,
                   const float* __restrict__ objlogit,
                   const unsigned int* __restrict__ mask,
                   const float2* __restrict__ cv2, float* __restrict__ partials) {
    const int tid = threadIdx.x;
    const int i0 = blockIdx.x * 256;
    const int i = i0 + tid;                 // BB*NN == 1050*256 exactly
    const int lane = tid & 63, wid = tid >> 6;
    const int b = i / NN;

    float obj_l, cls_l = 0.0f, reg_l = 0.0f, nfg = 0.0f;
    const unsigned int mk = mask[i];
    obj_l = bcef_(objlogit[i], mk ? 1.0f : 0.0f);

    __shared__ int s_list[256];
    __shared__ int s_gcls[256];
    __shared__ int s_wbase[4];
    __shared__ int s_cnt;

    unsigned long long bal = __ballot(mk != 0);
    int wpos = __popcll(bal & ((1ull << lane) - 1ull));
    if (lane == 0) s_wbase[wid] = __popcll(bal);
    __syncthreads();
    if (tid == 0) {
        int acc = 0;
        for (int w = 0; w < 4; ++w) { int t_ = s_wbase[w]; s_wbase[w] = acc; acc += t_; }
        s_cnt = acc;
    }
    __syncthreads();

    if (mk) {
        int e = s_wbase[wid] + wpos;
        s_list[e] = tid;
        nfg = 1.0f;
        float best = 3.0e30f; int bg = 0;
        for (int g = 0; g < MM; ++g) {
            if ((mk >> g) & 1u) {
                float cvv = cv2[(size_t)i * MM + g].x;
                if (cvv < best) { best = cvv; bg = g; }
            }
        }
        const float* t = tgt + ((size_t)b * MM + bg) * 5;
        s_gcls[e] = (int)t[0];
        const float* p = pred + (size_t)i * PD;
        float cx = p[0], cy = p[1], w = p[2], h = p[3];
        float px1 = cx - w * 0.5f, py1 = cy - h * 0.5f;
        float px2 = cx + w * 0.5f, py2 = cy + h * 0.5f;
        float tx1 = t[1] - t[3] * 0.5f, ty1 = t[2] - t[4] * 0.5f;
        float tx2 = t[1] + t[3] * 0.5f, ty2 = t[2] + t[4] * 0.5f;
        float ix1 = fmaxf(px1, tx1), iy1 = fmaxf(py1, ty1);
        float ix2 = fminf(px2, tx2), iy2 = fminf(py2, ty2);
        float inter = fmaxf(ix2 - ix1, 0.0f) * fmaxf(iy2 - iy1, 0.0f);
        float pa = fmaxf(px2 - px1, 0.0f) * fmaxf(py2 - py1, 0.0f);
        float ta = fmaxf(tx2 - tx1, 0.0f) * fmaxf(ty2 - ty1, 0.0f);
        float uni = pa + ta - inter + 1e-7f;
        float iou = inter / uni;
        float ex1 = fminf(px1, tx1), ey1 = fminf(py1, ty1);
        float ex2 = fmaxf(px2, tx2), ey2 = fmaxf(py2, ty2);
        float enclose = (ex2 - ex1) * (ey2 - ey1) + 1e-7f;
        float giou = iou - (enclose - uni) / enclose;
        reg_l = 1.0f - giou;
    }
    __syncthreads();

    const int cnt = s_cnt;
    const int nitems = cnt * NC;
    for (int item = tid; item < nitems; item += 256) {
        int e = item / NC;
        int c = item - e * NC;
        int gi = i0 + s_list[e];
        float x = pred[(size_t)gi * PD + 5 + c];
        cls_l += bcef_(x, (c == s_gcls[e]) ? 1.0f : 0.0f);
    }

    __shared__ float red[256];
    float sums[4] = {cls_l, obj_l, reg_l, nfg};
    float out4[4];
    for (int j = 0; j < 4; ++j) {
        red[tid] = sums[j];
        __syncthreads();
        for (int off = 128; off > 0; off >>= 1) {
            if (tid < off) red[tid] += red[tid + off];
            __syncthreads();
        }
        out4[j] = red[0];
        __syncthreads();
    }
    if (tid == 0) {
        float* pr = partials + (size_t)blockIdx.x * 4;
        pr[0] = out4[0]; pr[1] = out4[1]; pr[2] = out4[2]; pr[3] = out4[3];
    }
}

// ---- Kernel E: final deterministic reduction -----------------------------
__global__ void kE(const float* __restrict__ partials, int nblk, float* __restrict__ out) {
    __shared__ float red[256];
    float s[4] = {0, 0, 0, 0};
    for (int i = threadIdx.x; i < nblk; i += 256) {
        s[0] += partials[(size_t)i * 4 + 0];
        s[1] += partials[(size_t)i * 4 + 1];
        s[2] += partials[(size_t)i * 4 + 2];
        s[3] += partials[(size_t)i * 4 + 3];
    }
    float tot[4];
    for (int j = 0; j < 4; ++j) {
        red[threadIdx.x] = s[j];
        __syncthreads();
        for (int off = 128; off > 0; off >>= 1) {
            if (threadIdx.x < off) red[threadIdx.x] += red[threadIdx.x + off];
            __syncthreads();
        }
        tot[j] = red[0];
        __syncthreads();
    }
    if (threadIdx.x == 0) {
        float nfg = fmaxf(tot[3], 1.0f);
        out[0] = (tot[0] + tot[1] + 5.0f * tot[2]) / nfg;
    }
}

extern "C" void kernel_launch(void* const* d_in, const int* in_sizes, int n_in,
                              void* d_out, int out_size, void* d_ws, size_t ws_size,
                              hipStream_t stream) {
    const float* pred = (const float*)d_in[0];   // (B, N, 85) f32
    const float* tgt  = (const float*)d_in[1];   // (B, M, 5)  f32
    float* out = (float*)d_out;

    // Workspace layout (~71 MB)
    char* ws = (char*)d_ws;
    size_t off = 0;
    float2* cv2 = (float2*)(ws + off);              off += (size_t)BB * NN * MM * sizeof(float2);
    unsigned int* mask = (unsigned int*)(ws + off); off += (size_t)BB * NN * sizeof(unsigned int);
    float* objlogit = (float*)(ws + off);           off += (size_t)BB * NN * sizeof(float);
    float* partials = (float*)(ws + off);

    const int nblk = (BB * NN + 255) / 256;  // 1050

    // mask accumulates via atomicOr -> zero every call
    hipMemsetAsync(mask, 0, (size_t)BB * NN * sizeof(unsigned int), stream);

    kAB<<<2048, 256, 0, stream>>>(pred, tgt, objlogit, cv2);

    dim3 gC(MM, BB);                         // 32 x 32 = 1024 blocks
    kC<<<gC, 256, 0, stream>>>(cv2, mask);

    kD<<<nblk, 256, 0, stream>>>(pred, tgt, objlogit, mask, cv2, partials);

    kE<<<1, 256, 0, stream>>>(partials, nblk, out);
}

// Round 9
// 120.639 us; speedup vs baseline: 7.9423x; 1.4672x over previous
//
#include <hip/hip_runtime.h>
#include <math.h>

#define BB 32
#define NN 8400
#define MM 32
#define NC 80
#define PD 85
#define TOPK 10
#define FLT_BIG 3.4e38f

__device__ __forceinline__ float sigmoidf_(float x) { return 1.0f / (1.0f + expf(-x)); }
__device__ __forceinline__ float bcef_(float x, float t) {
    return fmaxf(x, 0.0f) - x * t + log1pf(expf(-fabsf(x)));
}

// fast hardware-native helpers (kAB only): v_exp/v_log/v_rcp/v_sqrt, ~1-2 ulp
__device__ __forceinline__ float frcp_(float x)  { return __builtin_amdgcn_rcpf(x); }
__device__ __forceinline__ float fsqrt_(float x) { return __builtin_amdgcn_sqrtf(x); }
__device__ __forceinline__ float fsig_(float x)  { return frcp_(1.0f + __expf(-x)); }

// ---- Kernel AB: wave-per-2-rows compute + LDS-tiled PLANAR store ----------
// Block = 256 threads = 16 consecutive rows (8 pairs): wave wid does pairs
// wid*2, wid*2+1. Results staged in LDS tile [16 n][32 g] (stride 33 pad),
// then written planar [b][g][n]: 32 g-rows x 16 n x 8B, coalesced 16B/thread.
__global__ void __launch_bounds__(256) kAB(const float* __restrict__ pred,
                                           const float* __restrict__ tgt,
                                           float* __restrict__ objlogit,
                                           float2* __restrict__ cv2) {
    const int tid = threadIdx.x;
    const int lane = tid & 63, wid = tid >> 6;
    const int rs = lane >> 5, g = lane & 31;
    const int b = blockIdx.y;
    const int tile = blockIdx.x;             // 525 tiles of 16 rows

    __shared__ float2 sm[16 * 33];

    for (int itr = 0; itr < 2; ++itr) {
        const int pl = wid * 2 + itr;        // pair-local 0..7
        const int r0 = tile * 16 + pl * 2;   // global row (even)
        const size_t off = ((size_t)b * NN + r0) * PD;
        float x0 = pred[off + lane];                             // pos 0..63
        float x1 = pred[off + 64 + lane];                        // pos 64..127
        float x2 = (lane < 42) ? pred[off + 128 + lane] : 0.0f;  // pos 128..169

        float cx0 = __shfl(x0, 0), cy0 = __shfl(x0, 1), w0 = __shfl(x0, 2), h0 = __shfl(x0, 3), ol0 = __shfl(x0, 4);
        float cx1 = __shfl(x1, 21), cy1 = __shfl(x1, 22), w1 = __shfl(x1, 23), h1 = __shfl(x1, 24), ol1 = __shfl(x1, 25);
        float so0 = fsig_(ol0), so1 = fsig_(ol1);
        if (lane == 0) objlogit[(size_t)b * NN + r0] = ol0;
        else if (lane == 1) objlogit[(size_t)b * NN + r0 + 1] = ol1;

        // class lq terms distributed one-per-lane (exec-masked regions)
        float a0 = 0.0f, a1 = 0.0f;
        if (lane >= 5)  a0 += __logf(1.0f - fsqrt_(fsig_(x0) * so0) + 1e-7f);
        if (lane < 21)  a0 += __logf(1.0f - fsqrt_(fsig_(x1) * so0) + 1e-7f);
        if (lane >= 26) a1 += __logf(1.0f - fsqrt_(fsig_(x1) * so1) + 1e-7f);
        if (lane < 42)  a1 += __logf(1.0f - fsqrt_(fsig_(x2) * so1) + 1e-7f);
        #pragma unroll
        for (int o = 32; o; o >>= 1) { a0 += __shfl_xor(a0, o); a1 += __shfl_xor(a1, o); }
        float base0 = -a0, base1 = -a1;

        float cxs = rs ? cx1 : cx0, cys = rs ? cy1 : cy0;
        float ws_ = rs ? w1 : w0, hs_ = rs ? h1 : h0;
        float sos = rs ? so1 : so0, bases = rs ? base1 : base0;
        float px1 = cxs - ws_ * 0.5f, py1 = cys - hs_ * 0.5f;
        float px2 = cxs + ws_ * 0.5f, py2 = cys + hs_ * 0.5f;
        float pa = fmaxf(px2 - px1, 0.0f) * fmaxf(py2 - py1, 0.0f);

        const float* t = tgt + ((size_t)b * MM + g) * 5;
        int gcls = (int)t[0];
        float gx1 = t[1] - t[3] * 0.5f, gy1 = t[2] - t[4] * 0.5f;
        float gx2 = t[1] + t[3] * 0.5f, gy2 = t[2] + t[4] * 0.5f;
        float ga = fmaxf(gx2 - gx1, 0.0f) * fmaxf(gy2 - gy1, 0.0f);

        int posn = rs * 85 + 5 + gcls;
        int k = posn >> 6, ls = posn & 63;
        float g0 = __shfl(x0, ls), g1 = __shfl(x1, ls), g2 = __shfl(x2, ls);
        float cl = (k == 0) ? g0 : ((k == 1) ? g1 : g2);

        float ix1 = fmaxf(gx1, px1), iy1 = fmaxf(gy1, py1);
        float ix2 = fminf(gx2, px2), iy2 = fminf(gy2, py2);
        float inter = fmaxf(ix2 - ix1, 0.0f) * fmaxf(iy2 - iy1, 0.0f);
        float uni = ga + pa - inter + 1e-7f;
        float iou = inter * frcp_(uni);
        bool inb = (cxs > gx1) && (cxs < gx2) && (cys > gy1) && (cys < gy2);
        float s = fsqrt_(fsig_(cl) * sos);
        float lp = __logf(s + 1e-7f);
        float lq = __logf(1.0f - s + 1e-7f);
        float cc = bases - lp + lq;
        float co = cc - 3.0f * __logf(iou + 1e-8f) + (inb ? 0.0f : 100000.0f);

        sm[(pl * 2 + rs) * 33 + g] = make_float2(co, inb ? iou : 0.0f);
    }
    __syncthreads();

    // planar write: g_row = tid>>3 (32 rows), 8 threads/row, 2 float2 each
    {
        const int g_row = tid >> 3;
        const int n0 = (tid & 7) * 2;
        float2 e0 = sm[n0 * 33 + g_row];
        float2 e1 = sm[(n0 + 1) * 33 + g_row];
        float4 v = make_float4(e0.x, e0.y, e1.x, e1.y);
        *reinterpret_cast<float4*>(&cv2[((size_t)b * MM + g_row) * NN + tile * 16 + n0]) = v;
    }
}

// ---- Kernel C: per-(b,g) dyn_k + assignment — PLANAR contiguous scan ------
// Identical per-thread scan order & merge as round 8 (bit-exact), new indexing.
__global__ void __launch_bounds__(256) kC(const float2* __restrict__ cv2,
                                          unsigned int* __restrict__ mask) {
    const int g = blockIdx.x, b = blockIdx.y, tid = threadIdx.x;
    const int wid = tid >> 6, lane = tid & 63;
    const float2* cvb = cv2 + ((size_t)b * MM + g) * NN;

    float ti[TOPK];
    float cv[TOPK]; int ci[TOPK];
    #pragma unroll
    for (int j = 0; j < TOPK; ++j) { ti[j] = -1.0f; cv[j] = FLT_BIG; ci[j] = 0x7fffffff; }

    for (int n = tid; n < NN; n += 256) {
        float2 e = cvb[n];
        float c = e.x, v = e.y;
        if (v > ti[TOPK - 1]) {
            ti[TOPK - 1] = v;
            #pragma unroll
            for (int j = TOPK - 1; j > 0; --j)
                if (ti[j] > ti[j - 1]) { float tmp = ti[j - 1]; ti[j - 1] = ti[j]; ti[j] = tmp; }
        }
        if (c < cv[TOPK - 1]) {
            cv[TOPK - 1] = c; ci[TOPK - 1] = n;
            #pragma unroll
            for (int j = TOPK - 1; j > 0; --j)
                if (cv[j] < cv[j - 1]) {
                    float tv = cv[j - 1]; cv[j - 1] = cv[j]; cv[j] = tv;
                    int tn = ci[j - 1]; ci[j - 1] = ci[j]; ci[j] = tn;
                }
        }
    }

    __shared__ float lv[256 * TOPK];
    __shared__ int   li[256 * TOPK];
    __shared__ float wv[4]; __shared__ int wn[4], wp[4];
    __shared__ float s_sum; __shared__ int s_dynk;

    #pragma unroll
    for (int j = 0; j < TOPK; ++j) lv[tid + 256 * j] = ti[j];
    __syncthreads();
    for (int p = 0; p < TOPK; ++p) {
        float bv = -2.0f; int bp = -1;
        #pragma unroll
        for (int j = 0; j < TOPK; ++j) {
            int idx = tid + 256 * j; float v = lv[idx];
            if (v > bv) { bv = v; bp = idx; }
        }
        for (int off = 32; off; off >>= 1) {
            float ov = __shfl_xor(bv, off); int op = __shfl_xor(bp, off);
            if (ov > bv || (ov == bv && op < bp)) { bv = ov; bp = op; }
        }
        if (lane == 0) { wv[wid] = bv; wp[wid] = bp; }
        __syncthreads();
        if (tid == 0) {
            float mb = wv[0]; int mp = wp[0];
            for (int w2 = 1; w2 < 4; ++w2)
                if (wv[w2] > mb || (wv[w2] == mb && wp[w2] < mp)) { mb = wv[w2]; mp = wp[w2]; }
            s_sum = (p == 0) ? mb : (s_sum + mb);
            lv[mp] = -2.0f;
        }
        __syncthreads();
    }
    if (tid == 0) {
        int k = (int)s_sum;
        if (k < 1) k = 1;
        if (k > TOPK) k = TOPK;
        s_dynk = k;
    }

    #pragma unroll
    for (int j = 0; j < TOPK; ++j) { lv[tid + 256 * j] = cv[j]; li[tid + 256 * j] = ci[j]; }
    __syncthreads();
    const int dynk = s_dynk;
    for (int p = 0; p < dynk; ++p) {
        float bv = FLT_BIG; int bn = 0x7fffffff; int bp = -1;
        #pragma unroll
        for (int j = 0; j < TOPK; ++j) {
            int idx = tid + 256 * j; float v = lv[idx]; int nn2 = li[idx];
            if (v < bv || (v == bv && nn2 < bn)) { bv = v; bn = nn2; bp = idx; }
        }
        for (int off = 32; off; off >>= 1) {
            float ov = __shfl_xor(bv, off);
            int on = __shfl_xor(bn, off);
            int op = __shfl_xor(bp, off);
            if (ov < bv || (ov == bv && on < bn)) { bv = ov; bn = on; bp = op; }
        }
        if (lane == 0) { wv[wid] = bv; wn[wid] = bn; wp[wid] = bp; }
        __syncthreads();
        if (tid == 0) {
            float mb = wv[0]; int mn = wn[0], mp = wp[0];
            for (int w2 = 1; w2 < 4; ++w2)
                if (wv[w2] < mb || (wv[w2] == mb && wn[w2] < mn)) { mb = wv[w2]; mn = wn[w2]; mp = wp[w2]; }
            lv[mp] = FLT_BIG; li[mp] = 0x7fffffff;
            if (mb < 5.0e4f)
                atomicOr(&mask[(size_t)b * NN + mn], 1u << g);
        }
        __syncthreads();
    }
}

// ---- Kernel D: compacted fg, item-parallel class BCE (planar cv2 read) ----
__global__ void __launch_bounds__(256) kD(const float* __restrict__ pred,
                   const float* __restrict__ tgt,
                   const float* __restrict__ objlogit,
                   const unsigned int* __restrict__ mask,
                   const float2* __restrict__ cv2, float* __restrict__ partials) {
    const int tid = threadIdx.x;
    const int i0 = blockIdx.x * 256;
    const int i = i0 + tid;                 // BB*NN == 1050*256 exactly
    const int lane = tid & 63, wid = tid >> 6;
    const int b = i / NN;
    const int n = i - b * NN;

    float obj_l, cls_l = 0.0f, reg_l = 0.0f, nfg = 0.0f;
    const unsigned int mk = mask[i];
    obj_l = bcef_(objlogit[i], mk ? 1.0f : 0.0f);

    __shared__ int s_list[256];
    __shared__ int s_gcls[256];
    __shared__ int s_wbase[4];
    __shared__ int s_cnt;

    unsigned long long bal = __ballot(mk != 0);
    int wpos = __popcll(bal & ((1ull << lane) - 1ull));
    if (lane == 0) s_wbase[wid] = __popcll(bal);
    __syncthreads();
    if (tid == 0) {
        int acc = 0;
        for (int w = 0; w < 4; ++w) { int t_ = s_wbase[w]; s_wbase[w] = acc; acc += t_; }
        s_cnt = acc;
    }
    __syncthreads();

    if (mk) {
        int e = s_wbase[wid] + wpos;
        s_list[e] = tid;
        nfg = 1.0f;
        float best = 3.0e30f; int bg = 0;
        for (int g = 0; g < MM; ++g) {
            if ((mk >> g) & 1u) {
                float cvv = cv2[((size_t)b * MM + g) * NN + n].x;
                if (cvv < best) { best = cvv; bg = g; }
            }
        }
        const float* t = tgt + ((size_t)b * MM + bg) * 5;
        s_gcls[e] = (int)t[0];
        const float* p = pred + (size_t)i * PD;
        float cx = p[0], cy = p[1], w = p[2], h = p[3];
        float px1 = cx - w * 0.5f, py1 = cy - h * 0.5f;
        float px2 = cx + w * 0.5f, py2 = cy + h * 0.5f;
        float tx1 = t[1] - t[3] * 0.5f, ty1 = t[2] - t[4] * 0.5f;
        float tx2 = t[1] + t[3] * 0.5f, ty2 = t[2] + t[4] * 0.5f;
        float ix1 = fmaxf(px1, tx1), iy1 = fmaxf(py1, ty1);
        float ix2 = fminf(px2, tx2), iy2 = fminf(py2, ty2);
        float inter = fmaxf(ix2 - ix1, 0.0f) * fmaxf(iy2 - iy1, 0.0f);
        float pa = fmaxf(px2 - px1, 0.0f) * fmaxf(py2 - py1, 0.0f);
        float ta = fmaxf(tx2 - tx1, 0.0f) * fmaxf(ty2 - ty1, 0.0f);
        float uni = pa + ta - inter + 1e-7f;
        float iou = inter / uni;
        float ex1 = fminf(px1, tx1), ey1 = fminf(py1, ty1);
        float ex2 = fmaxf(px2, tx2), ey2 = fmaxf(py2, ty2);
        float enclose = (ex2 - ex1) * (ey2 - ey1) + 1e-7f;
        float giou = iou - (enclose - uni) / enclose;
        reg_l = 1.0f - giou;
    }
    __syncthreads();

    const int cnt = s_cnt;
    const int nitems = cnt * NC;
    for (int item = tid; item < nitems; item += 256) {
        int e = item / NC;
        int c = item - e * NC;
        int gi = i0 + s_list[e];
        float x = pred[(size_t)gi * PD + 5 + c];
        cls_l += bcef_(x, (c == s_gcls[e]) ? 1.0f : 0.0f);
    }

    __shared__ float red[256];
    float sums[4] = {cls_l, obj_l, reg_l, nfg};
    float out4[4];
    for (int j = 0; j < 4; ++j) {
        red[tid] = sums[j];
        __syncthreads();
        for (int off = 128; off > 0; off >>= 1) {
            if (tid < off) red[tid] += red[tid + off];
            __syncthreads();
        }
        out4[j] = red[0];
        __syncthreads();
    }
    if (tid == 0) {
        float* pr = partials + (size_t)blockIdx.x * 4;
        pr[0] = out4[0]; pr[1] = out4[1]; pr[2] = out4[2]; pr[3] = out4[3];
    }
}

// ---- Kernel E: final deterministic reduction -----------------------------
__global__ void kE(const float* __restrict__ partials, int nblk, float* __restrict__ out) {
    __shared__ float red[256];
    float s[4] = {0, 0, 0, 0};
    for (int i = threadIdx.x; i < nblk; i += 256) {
        s[0] += partials[(size_t)i * 4 + 0];
        s[1] += partials[(size_t)i * 4 + 1];
        s[2] += partials[(size_t)i * 4 + 2];
        s[3] += partials[(size_t)i * 4 + 3];
    }
    float tot[4];
    for (int j = 0; j < 4; ++j) {
        red[threadIdx.x] = s[j];
        __syncthreads();
        for (int off = 128; off > 0; off >>= 1) {
            if (threadIdx.x < off) red[threadIdx.x] += red[threadIdx.x + off];
            __syncthreads();
        }
        tot[j] = red[0];
        __syncthreads();
    }
    if (threadIdx.x == 0) {
        float nfg = fmaxf(tot[3], 1.0f);
        out[0] = (tot[0] + tot[1] + 5.0f * tot[2]) / nfg;
    }
}

extern "C" void kernel_launch(void* const* d_in, const int* in_sizes, int n_in,
                              void* d_out, int out_size, void* d_ws, size_t ws_size,
                              hipStream_t stream) {
    const float* pred = (const float*)d_in[0];   // (B, N, 85) f32
    const float* tgt  = (const float*)d_in[1];   // (B, M, 5)  f32
    float* out = (float*)d_out;

    // Workspace layout (~71 MB); cv2 is PLANAR [b][g][n] float2
    char* ws = (char*)d_ws;
    size_t off = 0;
    float2* cv2 = (float2*)(ws + off);              off += (size_t)BB * MM * NN * sizeof(float2);
    unsigned int* mask = (unsigned int*)(ws + off); off += (size_t)BB * NN * sizeof(unsigned int);
    float* objlogit = (float*)(ws + off);           off += (size_t)BB * NN * sizeof(float);
    float* partials = (float*)(ws + off);

    const int nblk = (BB * NN + 255) / 256;  // 1050

    // mask accumulates via atomicOr -> zero every call
    hipMemsetAsync(mask, 0, (size_t)BB * NN * sizeof(unsigned int), stream);

    dim3 gAB(NN / 16, BB);                   // 525 x 32
    kAB<<<gAB, 256, 0, stream>>>(pred, tgt, objlogit, cv2);

    dim3 gC(MM, BB);                         // 32 x 32 = 1024 blocks
    kC<<<gC, 256, 0, stream>>>(cv2, mask);

    kD<<<nblk, 256, 0, stream>>>(pred, tgt, objlogit, mask, cv2, partials);

    kE<<<1, 256, 0, stream>>>(partials, nblk, out);
}

// Round 10
// 103.919 us; speedup vs baseline: 9.2202x; 1.1609x over previous
//
#include <hip/hip_runtime.h>
#include <math.h>

#define BB 32
#define NN 8400
#define MM 32
#define NC 80
#define PD 85
#define TOPK 10
#define FLT_BIG 3.4e38f

__device__ __forceinline__ float sigmoidf_(float x) { return 1.0f / (1.0f + expf(-x)); }
__device__ __forceinline__ float bcef_(float x, float t) {
    return fmaxf(x, 0.0f) - x * t + log1pf(expf(-fabsf(x)));
}

// fast hardware-native helpers (kAB only): v_exp/v_log/v_rcp/v_sqrt, ~1-2 ulp
__device__ __forceinline__ float frcp_(float x)  { return __builtin_amdgcn_rcpf(x); }
__device__ __forceinline__ float fsqrt_(float x) { return __builtin_amdgcn_sqrtf(x); }
__device__ __forceinline__ float fsig_(float x)  { return frcp_(1.0f + __expf(-x)); }

// ---- Kernel AB: wave-per-2-rows + in-box wave skip + planar LDS store -----
// Out-of-box (g,n) costs are provably output-irrelevant (in-box always ranks
// first; dyn_k <= #in-box when #in-box>=1; c==0 selections are dropped by the
// in_box check) -> waves with zero in-box lanes store flat (1e5, 0) and skip
// the entire transcendental chain (~46% of waves).
__global__ void __launch_bounds__(256) kAB(const float* __restrict__ pred,
                                           const float* __restrict__ tgt,
                                           float* __restrict__ objlogit,
                                           unsigned int* __restrict__ mask,
                                           float2* __restrict__ cv2) {
    const int tid = threadIdx.x;
    const int lane = tid & 63, wid = tid >> 6;
    const int rs = lane >> 5, g = lane & 31;
    const int b = blockIdx.y;
    const int tile = blockIdx.x;             // 525 tiles of 16 rows

    __shared__ float2 sm[16 * 33];

    // per-lane GT constants (same g for both iterations)
    const float* t = tgt + ((size_t)b * MM + g) * 5;
    const int gcls = (int)t[0];
    const float gx1 = t[1] - t[3] * 0.5f, gy1 = t[2] - t[4] * 0.5f;
    const float gx2 = t[1] + t[3] * 0.5f, gy2 = t[2] + t[4] * 0.5f;
    const float ga = fmaxf(gx2 - gx1, 0.0f) * fmaxf(gy2 - gy1, 0.0f);

    for (int itr = 0; itr < 2; ++itr) {
        const int pl = wid * 2 + itr;        // pair-local 0..7
        const int r0 = tile * 16 + pl * 2;   // global row (even)
        const size_t off = ((size_t)b * NN + r0) * PD;
        float x0 = pred[off + lane];                             // pos 0..63
        float x1 = pred[off + 64 + lane];                        // pos 64..127

        float cx0 = __shfl(x0, 0), cy0 = __shfl(x0, 1), w0 = __shfl(x0, 2), h0 = __shfl(x0, 3), ol0 = __shfl(x0, 4);
        float cx1 = __shfl(x1, 21), cy1 = __shfl(x1, 22), w1 = __shfl(x1, 23), h1 = __shfl(x1, 24), ol1 = __shfl(x1, 25);
        if (lane == 0) objlogit[(size_t)b * NN + r0] = ol0;
        else if (lane == 1) objlogit[(size_t)b * NN + r0 + 1] = ol1;
        else if (lane == 2) mask[(size_t)b * NN + r0] = 0u;      // fold memset in
        else if (lane == 3) mask[(size_t)b * NN + r0 + 1] = 0u;

        const float cxs = rs ? cx1 : cx0, cys = rs ? cy1 : cy0;
        const bool inb = (cxs > gx1) && (cxs < gx2) && (cys > gy1) && (cys < gy2);

        float2 res = make_float2(100000.0f, 0.0f);
        if (__ballot(inb) != 0ull) {         // wave-uniform branch
            float x2 = (lane < 42) ? pred[off + 128 + lane] : 0.0f; // pos 128..169
            float so0 = fsig_(ol0), so1 = fsig_(ol1);

            // class lq terms distributed one-per-lane (exec-masked regions)
            float a0 = 0.0f, a1 = 0.0f;
            if (lane >= 5)  a0 += __logf(1.0f - fsqrt_(fsig_(x0) * so0) + 1e-7f);
            if (lane < 21)  a0 += __logf(1.0f - fsqrt_(fsig_(x1) * so0) + 1e-7f);
            if (lane >= 26) a1 += __logf(1.0f - fsqrt_(fsig_(x1) * so1) + 1e-7f);
            if (lane < 42)  a1 += __logf(1.0f - fsqrt_(fsig_(x2) * so1) + 1e-7f);
            #pragma unroll
            for (int o = 32; o; o >>= 1) { a0 += __shfl_xor(a0, o); a1 += __shfl_xor(a1, o); }

            const float ws_ = rs ? w1 : w0, hs_ = rs ? h1 : h0;
            const float sos = rs ? so1 : so0, bases = rs ? -a1 : -a0;
            float px1 = cxs - ws_ * 0.5f, py1 = cys - hs_ * 0.5f;
            float px2 = cxs + ws_ * 0.5f, py2 = cys + hs_ * 0.5f;
            float pa = fmaxf(px2 - px1, 0.0f) * fmaxf(py2 - py1, 0.0f);

            // gather class logit (all lanes active: bpermute sources valid)
            int posn = rs * 85 + 5 + gcls;
            int k = posn >> 6, ls = posn & 63;
            float g0 = __shfl(x0, ls), g1 = __shfl(x1, ls), g2 = __shfl(x2, ls);
            float cl = (k == 0) ? g0 : ((k == 1) ? g1 : g2);

            float ix1 = fmaxf(gx1, px1), iy1 = fmaxf(gy1, py1);
            float ix2 = fminf(gx2, px2), iy2 = fminf(gy2, py2);
            float inter = fmaxf(ix2 - ix1, 0.0f) * fmaxf(iy2 - iy1, 0.0f);
            float uni = ga + pa - inter + 1e-7f;
            float iou = inter * frcp_(uni);
            float s = fsqrt_(fsig_(cl) * sos);
            float lp = __logf(s + 1e-7f);
            float lq = __logf(1.0f - s + 1e-7f);
            float cc = bases - lp + lq;
            float co = cc - 3.0f * __logf(iou + 1e-8f) + (inb ? 0.0f : 100000.0f);
            res = make_float2(co, inb ? iou : 0.0f);
        }
        sm[(pl * 2 + rs) * 33 + g] = res;
    }
    __syncthreads();

    // planar write: g_row = tid>>3 (32 rows), 8 threads/row, 2 float2 each
    {
        const int g_row = tid >> 3;
        const int n0 = (tid & 7) * 2;
        float2 e0 = sm[n0 * 33 + g_row];
        float2 e1 = sm[(n0 + 1) * 33 + g_row];
        float4 v = make_float4(e0.x, e0.y, e1.x, e1.y);
        *reinterpret_cast<float4*>(&cv2[((size_t)b * MM + g_row) * NN + tile * 16 + n0]) = v;
    }
}

// ---- Kernel C: per-(b,g) dyn_k + assignment — float4 planar scan ----------
// Same selection semantics (per-thread n strictly increasing; lex merges).
__global__ void __launch_bounds__(256) kC(const float2* __restrict__ cv2,
                                          unsigned int* __restrict__ mask) {
    const int g = blockIdx.x, b = blockIdx.y, tid = threadIdx.x;
    const int wid = tid >> 6, lane = tid & 63;
    const float2* cvb = cv2 + ((size_t)b * MM + g) * NN;

    float ti[TOPK];
    float cv[TOPK]; int ci[TOPK];
    #pragma unroll
    for (int j = 0; j < TOPK; ++j) { ti[j] = -1.0f; cv[j] = FLT_BIG; ci[j] = 0x7fffffff; }

    #define INSERT_CAND(cN, vN, nN)                                              \
        do {                                                                      \
            float c_ = (cN), v_ = (vN); int n_ = (nN);                            \
            if (v_ > ti[TOPK - 1]) {                                              \
                ti[TOPK - 1] = v_;                                                \
                _Pragma("unroll")                                                 \
                for (int j = TOPK - 1; j > 0; --j)                                \
                    if (ti[j] > ti[j - 1]) { float tm = ti[j-1]; ti[j-1] = ti[j]; ti[j] = tm; } \
            }                                                                     \
            if (c_ < cv[TOPK - 1]) {                                              \
                cv[TOPK - 1] = c_; ci[TOPK - 1] = n_;                             \
                _Pragma("unroll")                                                 \
                for (int j = TOPK - 1; j > 0; --j)                                \
                    if (cv[j] < cv[j - 1]) {                                      \
                        float tv = cv[j-1]; cv[j-1] = cv[j]; cv[j] = tv;          \
                        int tn = ci[j-1]; ci[j-1] = ci[j]; ci[j] = tn;            \
                    }                                                             \
            }                                                                     \
        } while (0)

    for (int n2 = tid; n2 < NN / 2; n2 += 256) {   // float4 = 2 elements, n increasing
        float4 q = *reinterpret_cast<const float4*>(cvb + 2 * n2);
        INSERT_CAND(q.x, q.y, 2 * n2);
        INSERT_CAND(q.z, q.w, 2 * n2 + 1);
    }
    #undef INSERT_CAND

    __shared__ float lv[256 * TOPK];
    __shared__ int   li[256 * TOPK];
    __shared__ float wv[4]; __shared__ int wn[4], wp[4];
    __shared__ float s_sum; __shared__ int s_dynk;

    #pragma unroll
    for (int j = 0; j < TOPK; ++j) lv[tid + 256 * j] = ti[j];
    __syncthreads();
    for (int p = 0; p < TOPK; ++p) {
        float bv = -2.0f; int bp = -1;
        #pragma unroll
        for (int j = 0; j < TOPK; ++j) {
            int idx = tid + 256 * j; float v = lv[idx];
            if (v > bv) { bv = v; bp = idx; }
        }
        for (int off = 32; off; off >>= 1) {
            float ov = __shfl_xor(bv, off); int op = __shfl_xor(bp, off);
            if (ov > bv || (ov == bv && op < bp)) { bv = ov; bp = op; }
        }
        if (lane == 0) { wv[wid] = bv; wp[wid] = bp; }
        __syncthreads();
        if (tid == 0) {
            float mb = wv[0]; int mp = wp[0];
            for (int w2 = 1; w2 < 4; ++w2)
                if (wv[w2] > mb || (wv[w2] == mb && wp[w2] < mp)) { mb = wv[w2]; mp = wp[w2]; }
            s_sum = (p == 0) ? mb : (s_sum + mb);
            lv[mp] = -2.0f;
        }
        __syncthreads();
    }
    if (tid == 0) {
        int k = (int)s_sum;
        if (k < 1) k = 1;
        if (k > TOPK) k = TOPK;
        s_dynk = k;
    }

    #pragma unroll
    for (int j = 0; j < TOPK; ++j) { lv[tid + 256 * j] = cv[j]; li[tid + 256 * j] = ci[j]; }
    __syncthreads();
    const int dynk = s_dynk;
    for (int p = 0; p < dynk; ++p) {
        float bv = FLT_BIG; int bn = 0x7fffffff; int bp = -1;
        #pragma unroll
        for (int j = 0; j < TOPK; ++j) {
            int idx = tid + 256 * j; float v = lv[idx]; int nn2 = li[idx];
            if (v < bv || (v == bv && nn2 < bn)) { bv = v; bn = nn2; bp = idx; }
        }
        for (int off = 32; off; off >>= 1) {
            float ov = __shfl_xor(bv, off);
            int on = __shfl_xor(bn, off);
            int op = __shfl_xor(bp, off);
            if (ov < bv || (ov == bv && on < bn)) { bv = ov; bn = on; bp = op; }
        }
        if (lane == 0) { wv[wid] = bv; wn[wid] = bn; wp[wid] = bp; }
        __syncthreads();
        if (tid == 0) {
            float mb = wv[0]; int mn = wn[0], mp = wp[0];
            for (int w2 = 1; w2 < 4; ++w2)
                if (wv[w2] < mb || (wv[w2] == mb && wn[w2] < mn)) { mb = wv[w2]; mn = wn[w2]; mp = wp[w2]; }
            lv[mp] = FLT_BIG; li[mp] = 0x7fffffff;
            if (mb < 5.0e4f)
                atomicOr(&mask[(size_t)b * NN + mn], 1u << g);
        }
        __syncthreads();
    }
}

// ---- Kernel D: compacted fg, item-parallel class BCE (unchanged) ----------
__global__ void __launch_bounds__(256) kD(const float* __restrict__ pred,
                   const float* __restrict__ tgt,
                   const float* __restrict__ objlogit,
                   const unsigned int* __restrict__ mask,
                   const float2* __restrict__ cv2, float* __restrict__ partials) {
    const int tid = threadIdx.x;
    const int i0 = blockIdx.x * 256;
    const int i = i0 + tid;                 // BB*NN == 1050*256 exactly
    const int lane = tid & 63, wid = tid >> 6;
    const int b = i / NN;
    const int n = i - b * NN;

    float obj_l, cls_l = 0.0f, reg_l = 0.0f, nfg = 0.0f;
    const unsigned int mk = mask[i];
    obj_l = bcef_(objlogit[i], mk ? 1.0f : 0.0f);

    __shared__ int s_list[256];
    __shared__ int s_gcls[256];
    __shared__ int s_wbase[4];
    __shared__ int s_cnt;

    unsigned long long bal = __ballot(mk != 0);
    int wpos = __popcll(bal & ((1ull << lane) - 1ull));
    if (lane == 0) s_wbase[wid] = __popcll(bal);
    __syncthreads();
    if (tid == 0) {
        int acc = 0;
        for (int w = 0; w < 4; ++w) { int t_ = s_wbase[w]; s_wbase[w] = acc; acc += t_; }
        s_cnt = acc;
    }
    __syncthreads();

    if (mk) {
        int e = s_wbase[wid] + wpos;
        s_list[e] = tid;
        nfg = 1.0f;
        float best = 3.0e30f; int bg = 0;
        for (int g = 0; g < MM; ++g) {
            if ((mk >> g) & 1u) {
                float cvv = cv2[((size_t)b * MM + g) * NN + n].x;
                if (cvv < best) { best = cvv; bg = g; }
            }
        }
        const float* t = tgt + ((size_t)b * MM + bg) * 5;
        s_gcls[e] = (int)t[0];
        const float* p = pred + (size_t)i * PD;
        float cx = p[0], cy = p[1], w = p[2], h = p[3];
        float px1 = cx - w * 0.5f, py1 = cy - h * 0.5f;
        float px2 = cx + w * 0.5f, py2 = cy + h * 0.5f;
        float tx1 = t[1] - t[3] * 0.5f, ty1 = t[2] - t[4] * 0.5f;
        float tx2 = t[1] + t[3] * 0.5f, ty2 = t[2] + t[4] * 0.5f;
        float ix1 = fmaxf(px1, tx1), iy1 = fmaxf(py1, ty1);
        float ix2 = fminf(px2, tx2), iy2 = fminf(py2, ty2);
        float inter = fmaxf(ix2 - ix1, 0.0f) * fmaxf(iy2 - iy1, 0.0f);
        float pa = fmaxf(px2 - px1, 0.0f) * fmaxf(py2 - py1, 0.0f);
        float ta = fmaxf(tx2 - tx1, 0.0f) * fmaxf(ty2 - ty1, 0.0f);
        float uni = pa + ta - inter + 1e-7f;
        float iou = inter / uni;
        float ex1 = fminf(px1, tx1), ey1 = fminf(py1, ty1);
        float ex2 = fmaxf(px2, tx2), ey2 = fmaxf(py2, ty2);
        float enclose = (ex2 - ex1) * (ey2 - ey1) + 1e-7f;
        float giou = iou - (enclose - uni) / enclose;
        reg_l = 1.0f - giou;
    }
    __syncthreads();

    const int cnt = s_cnt;
    const int nitems = cnt * NC;
    for (int item = tid; item < nitems; item += 256) {
        int e = item / NC;
        int c = item - e * NC;
        int gi = i0 + s_list[e];
        float x = pred[(size_t)gi * PD + 5 + c];
        cls_l += bcef_(x, (c == s_gcls[e]) ? 1.0f : 0.0f);
    }

    __shared__ float red[256];
    float sums[4] = {cls_l, obj_l, reg_l, nfg};
    float out4[4];
    for (int j = 0; j < 4; ++j) {
        red[tid] = sums[j];
        __syncthreads();
        for (int off = 128; off > 0; off >>= 1) {
            if (tid < off) red[tid] += red[tid + off];
            __syncthreads();
        }
        out4[j] = red[0];
        __syncthreads();
    }
    if (tid == 0) {
        float* pr = partials + (size_t)blockIdx.x * 4;
        pr[0] = out4[0]; pr[1] = out4[1]; pr[2] = out4[2]; pr[3] = out4[3];
    }
}

// ---- Kernel E: final deterministic reduction -----------------------------
__global__ void kE(const float* __restrict__ partials, int nblk, float* __restrict__ out) {
    __shared__ float red[256];
    float s[4] = {0, 0, 0, 0};
    for (int i = threadIdx.x; i < nblk; i += 256) {
        s[0] += partials[(size_t)i * 4 + 0];
        s[1] += partials[(size_t)i * 4 + 1];
        s[2] += partials[(size_t)i * 4 + 2];
        s[3] += partials[(size_t)i * 4 + 3];
    }
    float tot[4];
    for (int j = 0; j < 4; ++j) {
        red[threadIdx.x] = s[j];
        __syncthreads();
        for (int off = 128; off > 0; off >>= 1) {
            if (threadIdx.x < off) red[threadIdx.x] += red[threadIdx.x + off];
            __syncthreads();
        }
        tot[j] = red[0];
        __syncthreads();
    }
    if (threadIdx.x == 0) {
        float nfg = fmaxf(tot[3], 1.0f);
        out[0] = (tot[0] + tot[1] + 5.0f * tot[2]) / nfg;
    }
}

extern "C" void kernel_launch(void* const* d_in, const int* in_sizes, int n_in,
                              void* d_out, int out_size, void* d_ws, size_t ws_size,
                              hipStream_t stream) {
    const float* pred = (const float*)d_in[0];   // (B, N, 85) f32
    const float* tgt  = (const float*)d_in[1];   // (B, M, 5)  f32
    float* out = (float*)d_out;

    // Workspace layout (~71 MB); cv2 is PLANAR [b][g][n] float2
    char* ws = (char*)d_ws;
    size_t off = 0;
    float2* cv2 = (float2*)(ws + off);              off += (size_t)BB * MM * NN * sizeof(float2);
    unsigned int* mask = (unsigned int*)(ws + off); off += (size_t)BB * NN * sizeof(unsigned int);
    float* objlogit = (float*)(ws + off);           off += (size_t)BB * NN * sizeof(float);
    float* partials = (float*)(ws + off);

    const int nblk = (BB * NN + 255) / 256;  // 1050

    // mask is zeroed inside kAB (covers all B*N entries) before kC's atomicOr

    dim3 gAB(NN / 16, BB);                   // 525 x 32
    kAB<<<gAB, 256, 0, stream>>>(pred, tgt, objlogit, mask, cv2);

    dim3 gC(MM, BB);                         // 32 x 32 = 1024 blocks
    kC<<<gC, 256, 0, stream>>>(cv2, mask);

    kD<<<nblk, 256, 0, stream>>>(pred, tgt, objlogit, mask, cv2, partials);

    kE<<<1, 256, 0, stream>>>(partials, nblk, out);
}